// Round 1
// baseline (1974.262 us; speedup 1.0000x reference)
//
#include <hip/hip_runtime.h>
#include <math.h>

#define NB 512
#define DD 32
#define NPX 1024      // 32*32
#define NTOT 524288   // 512*1024
#define NC 512
#define CD 64

typedef float v2f __attribute__((ext_vector_type(2)));
#define PKFMA(a, b, c) __builtin_elementwise_fma((a), (b), (c))

// numpy pairwise-8 sum of squares over 64 contiguous elements.
__device__ __forceinline__ float np_sumsq64(const float* a, int stride) {
    float r[8];
    #pragma unroll
    for (int j = 0; j < 8; ++j) {
        float v = a[j * stride];
        r[j] = __fmul_rn(v, v);
    }
    #pragma unroll
    for (int i = 1; i < 8; ++i)
        #pragma unroll
        for (int j = 0; j < 8; ++j) {
            float v = a[(i * 8 + j) * stride];
            r[j] = __fadd_rn(r[j], __fmul_rn(v, v));
        }
    return __fadd_rn(__fadd_rn(__fadd_rn(r[0], r[1]), __fadd_rn(r[2], r[3])),
                     __fadd_rn(__fadd_rn(r[4], r[5]), __fadd_rn(r[6], r[7])));
}

// ---------------- conv1 (+ folded init: cnorm + loss-acc zero) ----------------
__global__ __launch_bounds__(256) void k_conv1(const float* __restrict__ x,
                                               const float* __restrict__ w,
                                               const float* __restrict__ bias,
                                               float* __restrict__ h1,
                                               const float* __restrict__ cb,
                                               float* __restrict__ cnorm,
                                               float* __restrict__ accv) {
    const int b = blockIdx.x;
    const int tid = threadIdx.x;
    {   // folded k_init: blocks 0..1 compute codebook norms; independent work
        int t = b * 256 + tid;
        if (t < NC)
            cnorm[t] = np_sumsq64(cb + (size_t)t * CD, 1);
        if (t == 0) accv[0] = 0.f;
    }
    __shared__ float xs[34][34];
    for (int i = tid; i < 34 * 34; i += 256) {
        int yy = i / 34, xx = i - yy * 34;
        float v = 0.f;
        if (yy >= 1 && yy <= 32 && xx >= 1 && xx <= 32)
            v = x[(size_t)b * NPX + (yy - 1) * 32 + (xx - 1)];
        xs[yy][xx] = v;
    }
    __syncthreads();
    for (int rep = 0; rep < 4; ++rep) {
        int px = tid + rep * 256;
        int y = px >> 5, xc = px & 31;
        v2f acc2[16];
        #pragma unroll
        for (int c = 0; c < 16; ++c) acc2[c] = v2f{0.f, 0.f};
        #pragma unroll
        for (int dy = 0; dy < 3; ++dy)
        #pragma unroll
        for (int dx = 0; dx < 3; ++dx) {
            float a = xs[y + dy][xc + dx];
            v2f av = {a, a};
            const v2f* wr = (const v2f*)(w + (dy * 3 + dx) * 32);
            #pragma unroll
            for (int c = 0; c < 16; ++c) acc2[c] = PKFMA(av, wr[c], acc2[c]);
        }
        float4* out = (float4*)(h1 + ((size_t)b * NPX + px) * 32);
        #pragma unroll
        for (int q = 0; q < 8; ++q) {
            float4 v;
            v.x = fmaxf(__fadd_rn(acc2[q*2+0].x, bias[q*4+0]), 0.f);
            v.y = fmaxf(__fadd_rn(acc2[q*2+0].y, bias[q*4+1]), 0.f);
            v.z = fmaxf(__fadd_rn(acc2[q*2+1].x, bias[q*4+2]), 0.f);
            v.w = fmaxf(__fadd_rn(acc2[q*2+1].y, bias[q*4+3]), 0.f);
            out[q] = v;
        }
    }
}

// ---------------- conv2: h1 -> relu -> h [512,32,32,64], wave-co-blocked ----------------
// Same structure as R12, but code-pair packed FMA (v_pk_fma_f32).
// Per-(pq,c) accumulation chain order is UNCHANGED (a0,a1,a2,a3 per ci0; s9,ci0
// ascending) -> bit-exact vs the scalar R12 version.
__global__ __launch_bounds__(512, 4) void k_conv2(const float* __restrict__ h1,
                                                  const float* __restrict__ w,
                                                  const float* __restrict__ bias,
                                                  float* __restrict__ h) {
    __shared__ float tile[32][10][34];   // 43.5 KB, [ci][row][x+1], zero-padded x
    const int blk = blockIdx.x;
    const int b = blk >> 2, strip = blk & 3;
    const int r0 = strip * 8;
    const int tid = threadIdx.x;
    for (int i = tid; i < 640; i += 512) {   // zero pad columns: 32ci x 10row x 2
        int ci = i / 20, rem = i - ci * 20;
        tile[ci][rem >> 1][(rem & 1) * 33] = 0.f;
    }
    #pragma unroll
    for (int r = 0; r < 5; ++r) {        // 2560 float4 = 10 rows x 32x x 8ci4
        int j = tid + r * 512;
        int ci4 = j & 7, xc = (j >> 3) & 31, ry = j >> 8;   // ry 0..9
        int gy = r0 - 1 + ry;
        float4 v = make_float4(0.f, 0.f, 0.f, 0.f);
        if (gy >= 0 && gy < 32)
            v = *(const float4*)(h1 + ((size_t)b * NPX + gy * 32 + xc) * 32 + ci4 * 4);
        tile[ci4 * 4 + 0][ry][xc + 1] = v.x;
        tile[ci4 * 4 + 1][ry][xc + 1] = v.y;
        tile[ci4 * 4 + 2][ry][xc + 1] = v.z;
        tile[ci4 * 4 + 3][ry][xc + 1] = v.w;
    }
    __syncthreads();
    const int lane = tid & 63;
    const int cgu = __builtin_amdgcn_readfirstlane(tid >> 6);   // wave id = co group
    const int xc = lane & 31, lrow = lane >> 5;
    v2f acc2[4][4];
    #pragma unroll
    for (int pq = 0; pq < 4; ++pq)
        #pragma unroll
        for (int j = 0; j < 4; ++j) acc2[pq][j] = v2f{0.f, 0.f};
    #pragma unroll 1
    for (int s9 = 0; s9 < 9; ++s9) {
        const int dy = s9 / 3, dx = s9 - dy * 3;
        const int xcd = xc + dx;
        #pragma unroll 1
        for (int ci0 = 0; ci0 < 32; ci0 += 4) {
            const float* wp = w + s9 * 2048 + ci0 * 64 + cgu * 8;  // uniform -> s_load
            v2f ws2[4][4];
            #pragma unroll
            for (int i = 0; i < 4; ++i)
                #pragma unroll
                for (int j = 0; j < 4; ++j)
                    ws2[i][j] = ((const v2f*)(wp + i * 64))[j];
            #pragma unroll
            for (int pq = 0; pq < 4; ++pq) {
                const int row = pq * 2 + lrow + dy;
                const float a0 = tile[ci0 + 0][row][xcd];
                const float a1 = tile[ci0 + 1][row][xcd];
                const float a2 = tile[ci0 + 2][row][xcd];
                const float a3 = tile[ci0 + 3][row][xcd];
                const v2f a0v = {a0, a0}, a1v = {a1, a1};
                const v2f a2v = {a2, a2}, a3v = {a3, a3};
                #pragma unroll
                for (int j = 0; j < 4; ++j) {
                    acc2[pq][j] = PKFMA(a0v, ws2[0][j], acc2[pq][j]);
                    acc2[pq][j] = PKFMA(a1v, ws2[1][j], acc2[pq][j]);
                    acc2[pq][j] = PKFMA(a2v, ws2[2][j], acc2[pq][j]);
                    acc2[pq][j] = PKFMA(a3v, ws2[3][j], acc2[pq][j]);
                }
            }
        }
    }
    const float* bi = bias + cgu * 8;    // uniform -> s_load
    #pragma unroll
    for (int pq = 0; pq < 4; ++pq) {
        const int pxl = pq * 64 + lane;  // 0..255 within strip
        float* outp = h + ((size_t)b * NPX + r0 * 32 + pxl) * 64 + cgu * 8;
        float4 v0, v1;
        v0.x = fmaxf(__fadd_rn(acc2[pq][0].x, bi[0]), 0.f);
        v0.y = fmaxf(__fadd_rn(acc2[pq][0].y, bi[1]), 0.f);
        v0.z = fmaxf(__fadd_rn(acc2[pq][1].x, bi[2]), 0.f);
        v0.w = fmaxf(__fadd_rn(acc2[pq][1].y, bi[3]), 0.f);
        v1.x = fmaxf(__fadd_rn(acc2[pq][2].x, bi[4]), 0.f);
        v1.y = fmaxf(__fadd_rn(acc2[pq][2].y, bi[5]), 0.f);
        v1.z = fmaxf(__fadd_rn(acc2[pq][3].x, bi[6]), 0.f);
        v1.w = fmaxf(__fadd_rn(acc2[pq][3].y, bi[7]), 0.f);
        ((float4*)outp)[0] = v0;
        ((float4*)outp)[1] = v1;
    }
}

// ---------------- codebook transpose: cb[512][64] -> cbT[64][512] ----------------
// Runs after conv2 (h1 dead) and before k_vq. Lives in the dead h1 region.
__global__ __launch_bounds__(256) void k_cbt(const float* __restrict__ cb,
                                             float* __restrict__ cbT) {
    int t = blockIdx.x * 256 + threadIdx.x;  // 0..32767
    int k = t >> 9, c = t & 511;
    cbT[t] = cb[c * 64 + k];
}

// ---------------- VQ: R12 structure, code-pair packed FMA ----------------
// Each v_pk_fma_f32 lane carries one code's accumulator; per-code chains are
// k=0..63 sequential, identical to the scalar R12 version -> bit-exact argmin.
__global__ __launch_bounds__(512, 6) void k_vq(const float* __restrict__ h,
                                               const float* __restrict__ cb,
                                               const float* __restrict__ cbT,
                                               const float* __restrict__ cnorm,
                                               int* __restrict__ idxout,
                                               float* __restrict__ fidx,
                                               float* __restrict__ lossacc) {
    __shared__ float4 Ats[16][128];   // 32 KB: [kgroup][px]
    __shared__ float Hs[128];
    __shared__ float mvs[4][128];
    __shared__ int   mis[4][128];
    const int tid = threadIdx.x;
    const int px = tid & 127, quarter = tid >> 7;   // wave-uniform quarter
    const size_t base = (size_t)blockIdx.x * 128;
    {
        const float4* src = (const float4*)(h + (base + px) * 64 + quarter * 16);
        #pragma unroll
        for (int j = 0; j < 4; ++j)
            Ats[quarter * 4 + j][px] = src[j];
    }
    __syncthreads();
    if (tid < 128) {   // numpy pairwise-8 ||h||^2 for pixel tid
        float f[64];
        #pragma unroll
        for (int kg = 0; kg < 16; ++kg) {
            float4 v = Ats[kg][tid];
            f[kg*4+0] = v.x; f[kg*4+1] = v.y; f[kg*4+2] = v.z; f[kg*4+3] = v.w;
        }
        float r[8];
        #pragma unroll
        for (int j = 0; j < 8; ++j) r[j] = __fmul_rn(f[j], f[j]);
        #pragma unroll
        for (int i = 1; i < 8; ++i)
            #pragma unroll
            for (int j = 0; j < 8; ++j)
                r[j] = __fadd_rn(r[j], __fmul_rn(f[i*8+j], f[i*8+j]));
        Hs[tid] = __fadd_rn(__fadd_rn(__fadd_rn(r[0], r[1]), __fadd_rn(r[2], r[3])),
                            __fadd_rn(__fadd_rn(r[4], r[5]), __fadd_rn(r[6], r[7])));
    }
    __syncthreads();
    const float H = Hs[px];
    float minv = 3.4e38f;
    int mini = 0;
    #pragma unroll 1
    for (int ch = 0; ch < 16; ++ch) {          // 16 chunks x 8 codes = this quarter's 128
        const int cbase = __builtin_amdgcn_readfirstlane(quarter * 128 + ch * 8);
        const float* cbt = cbT + cbase;                    // uniform -> s_load pairs
        v2f acc2[4];
        #pragma unroll
        for (int j = 0; j < 4; ++j) acc2[j] = v2f{0.f, 0.f};
        #pragma unroll
        for (int kg = 0; kg < 16; ++kg) {      // k ascending: sgemm order
            const float4 a = Ats[kg][px];      // 1 ds_read_b128 feeds 16 pk_fma
            const v2f* w0 = (const v2f*)(cbt + (kg * 4 + 0) * 512);
            const v2f* w1 = (const v2f*)(cbt + (kg * 4 + 1) * 512);
            const v2f* w2 = (const v2f*)(cbt + (kg * 4 + 2) * 512);
            const v2f* w3 = (const v2f*)(cbt + (kg * 4 + 3) * 512);
            const v2f ax = {a.x, a.x}, ay = {a.y, a.y};
            const v2f az = {a.z, a.z}, aw = {a.w, a.w};
            #pragma unroll
            for (int j = 0; j < 4; ++j) {
                acc2[j] = PKFMA(ax, w0[j], acc2[j]);
                acc2[j] = PKFMA(ay, w1[j], acc2[j]);
                acc2[j] = PKFMA(az, w2[j], acc2[j]);
                acc2[j] = PKFMA(aw, w3[j], acc2[j]);
            }
        }
        const float* cnc = cnorm + cbase;                   // uniform -> s_load
        #pragma unroll
        for (int c = 0; c < 8; ++c) {
            float accc = (c & 1) ? acc2[c >> 1].y : acc2[c >> 1].x;
            float d = __fadd_rn(__fsub_rn(H, __fmul_rn(2.f, accc)), cnc[c]);
            if (d < minv) { minv = d; mini = cbase + c; }   // strict < = first occurrence
        }
    }
    mvs[quarter][px] = minv;
    mis[quarter][px] = mini;
    __syncthreads();
    if (tid < 128) {
        float best = mvs[0][tid];              // quarters ascending: ties -> lower index
        int   bi   = mis[0][tid];
        #pragma unroll
        for (int q = 1; q < 4; ++q) {
            float v = mvs[q][tid];
            if (v < best) { best = v; bi = mis[q][tid]; }
        }
        idxout[base + tid] = bi;
        fidx[base + tid] = (float)bi;
        float ls = 0.f;
        const float* crow = cb + (size_t)bi * 64;
        #pragma unroll
        for (int kg = 0; kg < 16; ++kg) {
            float4 a = Ats[kg][tid];
            float d0 = crow[kg*4+0] - a.x;
            float d1 = crow[kg*4+1] - a.y;
            float d2 = crow[kg*4+2] - a.z;
            float d3 = crow[kg*4+3] - a.w;
            ls = fmaf(d0, d0, ls); ls = fmaf(d1, d1, ls);
            ls = fmaf(d2, d2, ls); ls = fmaf(d3, d3, ls);
        }
        #pragma unroll
        for (int off = 32; off > 0; off >>= 1)
            ls += __shfl_down(ls, off, 64);
        if ((tid & 63) == 0) atomicAdd(lossacc, ls);
    }
}

// ---------------- fc1: emb[512,65536] @ w1[65536,128], K-split partials ----------------
__global__ __launch_bounds__(256) void k_fc1(const int* __restrict__ idxw,
                                             const float* __restrict__ cb,
                                             const float* __restrict__ w1,
                                             float* __restrict__ part) {
    const int kchunk = blockIdx.x;       // 0..63  (16 pixels each)
    const int mtile  = blockIdx.y;       // 0..7   (64 images each)
    const int tid = threadIdx.x;
    const int wv = tid >> 6, lane = tid & 63;
    const int img = mtile * 64 + lane;
    const int pbase = kchunk * 16 + wv * 4;
    const int pbu = __builtin_amdgcn_readfirstlane(pbase);  // force uniform for s_loads
    int code[4];
    #pragma unroll
    for (int pp = 0; pp < 4; ++pp)
        code[pp] = idxw[(size_t)img * NPX + pbase + pp];
    for (int cc = 0; cc < 4; ++cc) {
        v2f acc2[16];
        #pragma unroll
        for (int c = 0; c < 16; ++c) acc2[c] = v2f{0.f, 0.f};
        #pragma unroll
        for (int pp = 0; pp < 4; ++pp) {
            const float* arow = cb + (size_t)code[pp] * 64;
            const float* wrow = w1 + ((size_t)(pbu + pp) * 64) * 128 + cc * 32;
            for (int kc = 0; kc < 4; ++kc) {
                float4 a4[4];
                #pragma unroll
                for (int q = 0; q < 4; ++q)
                    a4[q] = *(const float4*)(arow + kc * 16 + q * 4);
                #pragma unroll
                for (int kk = 0; kk < 16; ++kk) {
                    float av = ((const float*)a4)[kk];
                    v2f avv = {av, av};
                    const v2f* wr = (const v2f*)(wrow + (size_t)(kc * 16 + kk) * 128);
                    #pragma unroll
                    for (int c = 0; c < 16; ++c)
                        acc2[c] = PKFMA(avv, wr[c], acc2[c]);
                }
            }
        }
        float4* pout = (float4*)(part + ((size_t)kchunk * 512 + img) * 128 + cc * 32);
        #pragma unroll
        for (int q = 0; q < 8; ++q)
            pout[q] = make_float4(acc2[q*2+0].x, acc2[q*2+0].y,
                                  acc2[q*2+1].x, acc2[q*2+1].y);
    }
}

// ---------------- reduce partials + b1 + relu -> x0 [512,128] ----------------
__global__ __launch_bounds__(256) void k_reduce(const float* __restrict__ part,
                                                const float* __restrict__ b1,
                                                float* __restrict__ x0) {
    int t = blockIdx.x * 256 + threadIdx.x;  // 0..65535
    float s = b1[t & 127];
    for (int ch = 0; ch < 64; ++ch)
        s += part[(size_t)ch * 65536 + t];
    x0[t] = fmaxf(s, 0.f);
}

// ---------------- fused trunk + heads (+ folded vq-loss finalize) ----------------
__device__ __forceinline__ void mlp_layer(const float in[][16], float out[][16],
                                          const float* __restrict__ W,
                                          const float* __restrict__ bias,
                                          int tid, bool dorelu) {
    const int lane = tid & 63, wv = tid >> 6;
    const int img = lane & 15, cg = lane >> 4;
    const int c0 = wv * 32 + cg * 8;
    float acc[8] = {0,0,0,0,0,0,0,0};
    for (int k = 0; k < 128; ++k) {
        float a = in[k][img];
        float4 wA = *(const float4*)(W + (size_t)k * 128 + c0);
        float4 wB = *(const float4*)(W + (size_t)k * 128 + c0 + 4);
        acc[0] = fmaf(a, wA.x, acc[0]);
        acc[1] = fmaf(a, wA.y, acc[1]);
        acc[2] = fmaf(a, wA.z, acc[2]);
        acc[3] = fmaf(a, wA.w, acc[3]);
        acc[4] = fmaf(a, wB.x, acc[4]);
        acc[5] = fmaf(a, wB.y, acc[5]);
        acc[6] = fmaf(a, wB.z, acc[6]);
        acc[7] = fmaf(a, wB.w, acc[7]);
    }
    #pragma unroll
    for (int c = 0; c < 8; ++c) {
        float v = acc[c] + bias[c0 + c];
        if (dorelu) v = fmaxf(v, 0.f);
        out[c0 + c][img] = v;
    }
}

__global__ __launch_bounds__(256) void k_trunk(const float* __restrict__ x0,
        const float* __restrict__ w2, const float* __restrict__ b2,
        const float* __restrict__ w3, const float* __restrict__ b3,
        const float* __restrict__ wa1, const float* __restrict__ ba1,
        const float* __restrict__ wa2, const float* __restrict__ ba2,
        const float* __restrict__ wc1, const float* __restrict__ bc1,
        const float* __restrict__ wc2, const float* __restrict__ bc2,
        const float* __restrict__ wc3, const float* __restrict__ bc3,
        float* __restrict__ probs, float* __restrict__ value,
        const float* __restrict__ accv, float* __restrict__ vqloss) {
    __shared__ float bufA[128][16], bufB[128][16], bufC[128][16];
    __shared__ float lg[16][10];
    const int tid = threadIdx.x;
    const int m0 = blockIdx.x * 16;
    if (blockIdx.x == 0 && tid == 0)     // folded k_vqfinal (k_vq complete: stream order)
        vqloss[0] = accv[0] * 1.25f / 33554432.f;
    for (int r = 0; r < 2; ++r) {
        int j = tid + r * 256;                 // 0..511
        int img = j >> 5, k4 = j & 31;
        float4 v = *(const float4*)(x0 + (size_t)(m0 + img) * 128 + k4 * 4);
        bufA[k4*4+0][img] = v.x;
        bufA[k4*4+1][img] = v.y;
        bufA[k4*4+2][img] = v.z;
        bufA[k4*4+3][img] = v.w;
    }
    __syncthreads();
    mlp_layer(bufA, bufB, w2, b2, tid, true);   __syncthreads();
    mlp_layer(bufB, bufC, w3, b3, tid, true);   __syncthreads();  // C = e3
    mlp_layer(bufC, bufA, wa1, ba1, tid, true); __syncthreads();  // A = a1
    if (tid < 160) {
        int img = tid & 15, col = tid >> 4;     // col 0..9
        float s = 0.f;
        for (int k = 0; k < 128; ++k)
            s = fmaf(bufA[k][img], wa2[(size_t)k * 10 + col], s);
        lg[img][col] = s + ba2[col];
    }
    __syncthreads();
    if (tid < 16) {
        int img = tid;
        float m = lg[img][0];
        #pragma unroll
        for (int c = 1; c < 10; ++c) m = fmaxf(m, lg[img][c]);
        float e[10]; float s = 0.f;
        #pragma unroll
        for (int c = 0; c < 10; ++c) { e[c] = expf(lg[img][c] - m); s += e[c]; }
        float inv = 1.f / s;
        #pragma unroll
        for (int c = 0; c < 10; ++c)
            probs[(size_t)(m0 + img) * 10 + c] = e[c] * inv;
    }
    __syncthreads();
    mlp_layer(bufC, bufB, wc1, bc1, tid, true); __syncthreads();
    mlp_layer(bufB, bufA, wc2, bc2, tid, true); __syncthreads();  // A = c2
    if (tid < 16) {
        int img = tid;
        float s = 0.f;
        for (int k = 0; k < 128; ++k)
            s = fmaf(bufA[k][img], wc3[k], s);
        value[m0 + img] = s + bc3[0];
    }
}

extern "C" void kernel_launch(void* const* d_in, const int* in_sizes, int n_in,
                              void* d_out, int out_size, void* d_ws, size_t ws_size,
                              hipStream_t stream) {
    const float* x   = (const float*)d_in[0];
    const float* c1w = (const float*)d_in[1];
    const float* c1b = (const float*)d_in[2];
    const float* c2w = (const float*)d_in[3];
    const float* c2b = (const float*)d_in[4];
    const float* cb  = (const float*)d_in[5];
    const float* w1  = (const float*)d_in[6];
    const float* b1  = (const float*)d_in[7];
    const float* w2  = (const float*)d_in[8];
    const float* b2  = (const float*)d_in[9];
    const float* w3  = (const float*)d_in[10];
    const float* b3  = (const float*)d_in[11];
    const float* wa1 = (const float*)d_in[12];
    const float* ba1 = (const float*)d_in[13];
    const float* wa2 = (const float*)d_in[14];
    const float* ba2 = (const float*)d_in[15];
    const float* wc1 = (const float*)d_in[16];
    const float* bc1 = (const float*)d_in[17];
    const float* wc2 = (const float*)d_in[18];
    const float* bc2 = (const float*)d_in[19];
    const float* wc3 = (const float*)d_in[20];
    const float* bc3 = (const float*)d_in[21];

    float* out = (float*)d_out;
    float* ws  = (float*)d_ws;

    // workspace layout (floats):
    float* h1    = ws;                                   // 16,777,216  (dead after conv2)
    float* part  = ws;                                   //  4,194,304  (reuses h1 region)
    float* x0    = ws + (size_t)4 * 1024 * 1024;         //     65,536  (inside dead h1)
    float* cbt   = ws + (size_t)4259840;                 //     32,768  (inside dead h1,
                                                         //      past x0; written post-conv2,
                                                         //      read only by k_vq)
    float* h     = ws + (size_t)16 * 1024 * 1024;        // 33,554,432
    int*   idxw  = (int*)(ws + (size_t)50331648);        //    524,288 ints
    float* cn    = ws + (size_t)50855936;                //        512
    float* accv  = ws + (size_t)50856448;                //          1

    hipLaunchKernelGGL(k_conv1,  dim3(512),   dim3(256), 0, stream, x, c1w, c1b, h1,
                       cb, cn, accv);
    hipLaunchKernelGGL(k_conv2,  dim3(2048),  dim3(512), 0, stream, h1, c2w, c2b, h);
    hipLaunchKernelGGL(k_cbt,    dim3(128),   dim3(256), 0, stream, cb, cbt);
    hipLaunchKernelGGL(k_vq,     dim3(4096),  dim3(512), 0, stream, h, cb, cbt, cn,
                       idxw, out + 5633, accv);
    hipLaunchKernelGGL(k_fc1,    dim3(64, 8), dim3(256), 0, stream, idxw, cb, w1, part);
    hipLaunchKernelGGL(k_reduce, dim3(256),   dim3(256), 0, stream, part, b1, x0);
    hipLaunchKernelGGL(k_trunk,  dim3(32),    dim3(256), 0, stream, x0,
                       w2, b2, w3, b3, wa1, ba1, wa2, ba2,
                       wc1, bc1, wc2, bc2, wc3, bc3,
                       out, out + 5120, accv, out + 5632);
}

// Round 3
// 1225.146 us; speedup vs baseline: 1.6115x; 1.6115x over previous
//
#include <hip/hip_runtime.h>
#include <math.h>

#define NB 512
#define DD 32
#define NPX 1024      // 32*32
#define NTOT 524288   // 512*1024
#define NC 512
#define CD 64

typedef float v2f __attribute__((ext_vector_type(2)));

__device__ __forceinline__ v2f pkfma(v2f a, v2f b, v2f c) {
    return __builtin_elementwise_fma(a, b, c);
}
__device__ __forceinline__ v2f splat2(float s) { v2f r; r.x = s; r.y = s; return r; }

// numpy pairwise-8 sum of squares over 64 contiguous elements.
__device__ __forceinline__ float np_sumsq64(const float* a, int stride) {
    float r[8];
    #pragma unroll
    for (int j = 0; j < 8; ++j) {
        float v = a[j * stride];
        r[j] = __fmul_rn(v, v);
    }
    #pragma unroll
    for (int i = 1; i < 8; ++i)
        #pragma unroll
        for (int j = 0; j < 8; ++j) {
            float v = a[(i * 8 + j) * stride];
            r[j] = __fadd_rn(r[j], __fmul_rn(v, v));
        }
    return __fadd_rn(__fadd_rn(__fadd_rn(r[0], r[1]), __fadd_rn(r[2], r[3])),
                     __fadd_rn(__fadd_rn(r[4], r[5]), __fadd_rn(r[6], r[7])));
}

// ---------------- conv1 (+ folded init: cnorm + loss-acc zero) ----------------
__global__ __launch_bounds__(256) void k_conv1(const float* __restrict__ x,
                                               const float* __restrict__ w,
                                               const float* __restrict__ bias,
                                               float* __restrict__ h1,
                                               const float* __restrict__ cb,
                                               float* __restrict__ cnorm,
                                               float* __restrict__ accv) {
    const int b = blockIdx.x;
    const int tid = threadIdx.x;
    {   // folded k_init: blocks 0..1 compute codebook norms; independent work
        int t = b * 256 + tid;
        if (t < NC)
            cnorm[t] = np_sumsq64(cb + (size_t)t * CD, 1);
        if (t == 0) accv[0] = 0.f;
    }
    __shared__ float xs[34][34];
    for (int i = tid; i < 34 * 34; i += 256) {
        int yy = i / 34, xx = i - yy * 34;
        float v = 0.f;
        if (yy >= 1 && yy <= 32 && xx >= 1 && xx <= 32)
            v = x[(size_t)b * NPX + (yy - 1) * 32 + (xx - 1)];
        xs[yy][xx] = v;
    }
    __syncthreads();
    for (int rep = 0; rep < 4; ++rep) {
        int px = tid + rep * 256;
        int y = px >> 5, xc = px & 31;
        v2f acc2[16];
        #pragma unroll
        for (int c = 0; c < 16; ++c) acc2[c] = splat2(0.f);
        #pragma unroll
        for (int dy = 0; dy < 3; ++dy)
        #pragma unroll
        for (int dx = 0; dx < 3; ++dx) {
            float a = xs[y + dy][xc + dx];
            v2f av = splat2(a);
            const v2f* wr = (const v2f*)(w + (dy * 3 + dx) * 32);
            #pragma unroll
            for (int c = 0; c < 16; ++c) acc2[c] = pkfma(av, wr[c], acc2[c]);
        }
        float4* out = (float4*)(h1 + ((size_t)b * NPX + px) * 32);
        #pragma unroll
        for (int q = 0; q < 8; ++q) {
            float4 v;
            v.x = fmaxf(__fadd_rn(acc2[q*2+0].x, bias[q*4+0]), 0.f);
            v.y = fmaxf(__fadd_rn(acc2[q*2+0].y, bias[q*4+1]), 0.f);
            v.z = fmaxf(__fadd_rn(acc2[q*2+1].x, bias[q*4+2]), 0.f);
            v.w = fmaxf(__fadd_rn(acc2[q*2+1].y, bias[q*4+3]), 0.f);
            out[q] = v;
        }
    }
}

// ---------------- conv2: h1 -> relu -> h [512,32,32,64], wave-co-blocked ----------------
// (R12 passing version, proven scalar form)
__global__ __launch_bounds__(512, 4) void k_conv2(const float* __restrict__ h1,
                                                  const float* __restrict__ w,
                                                  const float* __restrict__ bias,
                                                  float* __restrict__ h) {
    __shared__ float tile[32][10][34];   // 43.5 KB, [ci][row][x+1], zero-padded x
    const int blk = blockIdx.x;
    const int b = blk >> 2, strip = blk & 3;
    const int r0 = strip * 8;
    const int tid = threadIdx.x;
    for (int i = tid; i < 640; i += 512) {   // zero pad columns: 32ci x 10row x 2
        int ci = i / 20, rem = i - ci * 20;
        tile[ci][rem >> 1][(rem & 1) * 33] = 0.f;
    }
    #pragma unroll
    for (int r = 0; r < 5; ++r) {        // 2560 float4 = 10 rows x 32x x 8ci4
        int j = tid + r * 512;
        int ci4 = j & 7, xc = (j >> 3) & 31, ry = j >> 8;   // ry 0..9
        int gy = r0 - 1 + ry;
        float4 v = make_float4(0.f, 0.f, 0.f, 0.f);
        if (gy >= 0 && gy < 32)
            v = *(const float4*)(h1 + ((size_t)b * NPX + gy * 32 + xc) * 32 + ci4 * 4);
        tile[ci4 * 4 + 0][ry][xc + 1] = v.x;
        tile[ci4 * 4 + 1][ry][xc + 1] = v.y;
        tile[ci4 * 4 + 2][ry][xc + 1] = v.z;
        tile[ci4 * 4 + 3][ry][xc + 1] = v.w;
    }
    __syncthreads();
    const int lane = tid & 63;
    const int cgu = __builtin_amdgcn_readfirstlane(tid >> 6);   // wave id = co group
    const int xc = lane & 31, lrow = lane >> 5;
    float acc[4][8];
    #pragma unroll
    for (int pq = 0; pq < 4; ++pq)
        #pragma unroll
        for (int c = 0; c < 8; ++c) acc[pq][c] = 0.f;
    #pragma unroll 1
    for (int s9 = 0; s9 < 9; ++s9) {
        const int dy = s9 / 3, dx = s9 - dy * 3;
        const int xcd = xc + dx;
        #pragma unroll 1
        for (int ci0 = 0; ci0 < 32; ci0 += 4) {
            const float* wp = w + s9 * 2048 + ci0 * 64 + cgu * 8;  // uniform -> s_load
            float ws[4][8];
            #pragma unroll
            for (int i = 0; i < 4; ++i)
                #pragma unroll
                for (int c = 0; c < 8; ++c)
                    ws[i][c] = wp[i * 64 + c];
            #pragma unroll
            for (int pq = 0; pq < 4; ++pq) {
                const int row = pq * 2 + lrow + dy;
                const float a0 = tile[ci0 + 0][row][xcd];
                const float a1 = tile[ci0 + 1][row][xcd];
                const float a2 = tile[ci0 + 2][row][xcd];
                const float a3 = tile[ci0 + 3][row][xcd];
                #pragma unroll
                for (int c = 0; c < 8; ++c) {
                    acc[pq][c] = fmaf(a0, ws[0][c], acc[pq][c]);
                    acc[pq][c] = fmaf(a1, ws[1][c], acc[pq][c]);
                    acc[pq][c] = fmaf(a2, ws[2][c], acc[pq][c]);
                    acc[pq][c] = fmaf(a3, ws[3][c], acc[pq][c]);
                }
            }
        }
    }
    const float* bi = bias + cgu * 8;    // uniform -> s_load
    #pragma unroll
    for (int pq = 0; pq < 4; ++pq) {
        const int pxl = pq * 64 + lane;  // 0..255 within strip
        float* outp = h + ((size_t)b * NPX + r0 * 32 + pxl) * 64 + cgu * 8;
        float4 v0, v1;
        v0.x = fmaxf(__fadd_rn(acc[pq][0], bi[0]), 0.f);
        v0.y = fmaxf(__fadd_rn(acc[pq][1], bi[1]), 0.f);
        v0.z = fmaxf(__fadd_rn(acc[pq][2], bi[2]), 0.f);
        v0.w = fmaxf(__fadd_rn(acc[pq][3], bi[3]), 0.f);
        v1.x = fmaxf(__fadd_rn(acc[pq][4], bi[4]), 0.f);
        v1.y = fmaxf(__fadd_rn(acc[pq][5], bi[5]), 0.f);
        v1.z = fmaxf(__fadd_rn(acc[pq][6], bi[6]), 0.f);
        v1.w = fmaxf(__fadd_rn(acc[pq][7], bi[7]), 0.f);
        ((float4*)outp)[0] = v0;
        ((float4*)outp)[1] = v1;
    }
}

// ---------------- VQ: pixel-pair pk_fma; codebook path identical to R12 ----------------
// Lane = pixel-pair (2 px in one v_pk_fma); wave = 64-code octant.
// Per-pixel per-code k-chains are k=0..63 sequential with the same scalar
// epilogue ops as R12 -> bit-exact argmin (code visit order also preserved:
// 8-code chunks ascending within octant, octants ascending in the final fold).
__global__ __launch_bounds__(512, 4) void k_vq(const float* __restrict__ h,
                                               const float* __restrict__ cb,
                                               const float* __restrict__ cnorm,
                                               int* __restrict__ idxout,
                                               float* __restrict__ fidx,
                                               float* __restrict__ lossacc) {
    __shared__ __attribute__((aligned(16))) float A2f[64 * 128]; // 32 KB: A2f[k*128+px] = h[base+px][k]
    __shared__ float Hs[128];
    __shared__ float mvs[8][128];
    __shared__ int   mis[8][128];
    const int tid = threadIdx.x;
    const size_t base = (size_t)blockIdx.x * 128;
    {   // stage: transpose h rows into [k][px] (lane-consecutive ds_write_b32)
        const int px = tid & 127, qq = tid >> 7;
        const float4* src = (const float4*)(h + (base + px) * 64 + qq * 16);
        #pragma unroll
        for (int j = 0; j < 4; ++j) {
            float4 v = src[j];
            const int k0 = qq * 16 + j * 4;
            A2f[(k0 + 0) * 128 + px] = v.x;
            A2f[(k0 + 1) * 128 + px] = v.y;
            A2f[(k0 + 2) * 128 + px] = v.z;
            A2f[(k0 + 3) * 128 + px] = v.w;
        }
    }
    __syncthreads();
    if (tid < 128) {   // numpy pairwise-8 ||h||^2 for pixel tid
        float f[64];
        #pragma unroll
        for (int k = 0; k < 64; ++k) f[k] = A2f[k * 128 + tid];
        float r[8];
        #pragma unroll
        for (int j = 0; j < 8; ++j) r[j] = __fmul_rn(f[j], f[j]);
        #pragma unroll
        for (int i = 1; i < 8; ++i)
            #pragma unroll
            for (int j = 0; j < 8; ++j)
                r[j] = __fadd_rn(r[j], __fmul_rn(f[i*8+j], f[i*8+j]));
        Hs[tid] = __fadd_rn(__fadd_rn(__fadd_rn(r[0], r[1]), __fadd_rn(r[2], r[3])),
                            __fadd_rn(__fadd_rn(r[4], r[5]), __fadd_rn(r[6], r[7])));
    }
    __syncthreads();
    const int p = tid & 63;                                     // pixel-pair lane
    const int oct = __builtin_amdgcn_readfirstlane(tid >> 6);   // wave id = code octant
    v2f av[32];                       // k = 0..31 hoisted to regs (64 VGPR)
    #pragma unroll
    for (int k = 0; k < 32; ++k)
        av[k] = *(const v2f*)(A2f + k * 128 + 2 * p);
    const float H0 = Hs[2 * p], H1 = Hs[2 * p + 1];
    float minv0 = 3.4e38f, minv1 = 3.4e38f;
    int mini0 = 0, mini1 = 0;
    #pragma unroll 1
    for (int ch = 0; ch < 8; ++ch) {        // 8 chunks x 8 codes = this octant's 64
        // keep the k=32..63 LDS reads inside the loop (no LICM -> no VGPR blowup)
        asm volatile("" ::: "memory");
        const int cbase = __builtin_amdgcn_readfirstlane(oct * 64 + ch * 8);
        const float* cbc = cb + ((size_t)cbase << 6);      // row-major, uniform -> s_load
        v2f acc2[8];
        #pragma unroll
        for (int c = 0; c < 8; ++c) acc2[c] = splat2(0.f);
        #pragma unroll
        for (int kg = 0; kg < 8; ++kg) {       // k 0..31 from registers
            #pragma unroll
            for (int c = 0; c < 8; ++c) {
                const float* wr = cbc + c * 64 + kg * 4;
                acc2[c] = pkfma(av[kg*4+0], splat2(wr[0]), acc2[c]);
                acc2[c] = pkfma(av[kg*4+1], splat2(wr[1]), acc2[c]);
                acc2[c] = pkfma(av[kg*4+2], splat2(wr[2]), acc2[c]);
                acc2[c] = pkfma(av[kg*4+3], splat2(wr[3]), acc2[c]);
            }
        }
        #pragma unroll
        for (int kg = 8; kg < 16; ++kg) {      // k 32..63 from LDS (lane-consecutive b64)
            v2f ah[4];
            #pragma unroll
            for (int j = 0; j < 4; ++j)
                ah[j] = *(const v2f*)(A2f + (kg * 4 + j) * 128 + 2 * p);
            #pragma unroll
            for (int c = 0; c < 8; ++c) {
                const float* wr = cbc + c * 64 + kg * 4;
                acc2[c] = pkfma(ah[0], splat2(wr[0]), acc2[c]);
                acc2[c] = pkfma(ah[1], splat2(wr[1]), acc2[c]);
                acc2[c] = pkfma(ah[2], splat2(wr[2]), acc2[c]);
                acc2[c] = pkfma(ah[3], splat2(wr[3]), acc2[c]);
            }
        }
        const float* cnc = cnorm + cbase;                   // uniform -> s_load
        #pragma unroll
        for (int c = 0; c < 8; ++c) {
            float d0 = __fadd_rn(__fsub_rn(H0, __fmul_rn(2.f, acc2[c].x)), cnc[c]);
            float d1 = __fadd_rn(__fsub_rn(H1, __fmul_rn(2.f, acc2[c].y)), cnc[c]);
            if (d0 < minv0) { minv0 = d0; mini0 = cbase + c; }  // strict < = first occurrence
            if (d1 < minv1) { minv1 = d1; mini1 = cbase + c; }
        }
    }
    mvs[oct][2*p]   = minv0;  mis[oct][2*p]   = mini0;
    mvs[oct][2*p+1] = minv1;  mis[oct][2*p+1] = mini1;
    __syncthreads();
    if (tid < 128) {
        float best = mvs[0][tid];              // octants ascending: ties -> lower index
        int   bi   = mis[0][tid];
        #pragma unroll
        for (int q = 1; q < 8; ++q) {
            float v = mvs[q][tid];
            if (v < best) { best = v; bi = mis[q][tid]; }
        }
        idxout[base + tid] = bi;
        fidx[base + tid] = (float)bi;
        float ls = 0.f;
        const float* crow = cb + (size_t)bi * 64;
        #pragma unroll
        for (int k = 0; k < 64; k += 4) {      // same chain order as R12 (k ascending)
            float d0 = crow[k+0] - A2f[(k+0)*128 + tid];
            float d1 = crow[k+1] - A2f[(k+1)*128 + tid];
            float d2 = crow[k+2] - A2f[(k+2)*128 + tid];
            float d3 = crow[k+3] - A2f[(k+3)*128 + tid];
            ls = fmaf(d0, d0, ls); ls = fmaf(d1, d1, ls);
            ls = fmaf(d2, d2, ls); ls = fmaf(d3, d3, ls);
        }
        #pragma unroll
        for (int off = 32; off > 0; off >>= 1)
            ls += __shfl_down(ls, off, 64);
        if ((tid & 63) == 0) atomicAdd(lossacc, ls);
    }
}

// ---------------- fc1: emb[512,65536] @ w1[65536,128], K-split partials ----------------
__global__ __launch_bounds__(256) void k_fc1(const int* __restrict__ idxw,
                                             const float* __restrict__ cb,
                                             const float* __restrict__ w1,
                                             float* __restrict__ part) {
    const int kchunk = blockIdx.x;       // 0..63  (16 pixels each)
    const int mtile  = blockIdx.y;       // 0..7   (64 images each)
    const int tid = threadIdx.x;
    const int wv = tid >> 6, lane = tid & 63;
    const int img = mtile * 64 + lane;
    const int pbase = kchunk * 16 + wv * 4;
    const int pbu = __builtin_amdgcn_readfirstlane(pbase);  // force uniform for s_loads
    int code[4];
    #pragma unroll
    for (int pp = 0; pp < 4; ++pp)
        code[pp] = idxw[(size_t)img * NPX + pbase + pp];
    for (int cc = 0; cc < 4; ++cc) {
        v2f acc2[16];
        #pragma unroll
        for (int c = 0; c < 16; ++c) acc2[c] = splat2(0.f);
        #pragma unroll
        for (int pp = 0; pp < 4; ++pp) {
            const float* arow = cb + (size_t)code[pp] * 64;
            const float* wrow = w1 + ((size_t)(pbu + pp) * 64) * 128 + cc * 32;
            for (int kc = 0; kc < 4; ++kc) {
                float4 a4[4];
                #pragma unroll
                for (int q = 0; q < 4; ++q)
                    a4[q] = *(const float4*)(arow + kc * 16 + q * 4);
                #pragma unroll
                for (int kk = 0; kk < 16; ++kk) {
                    float av = ((const float*)a4)[kk];
                    v2f avv = splat2(av);
                    const v2f* wr = (const v2f*)(wrow + (size_t)(kc * 16 + kk) * 128);
                    #pragma unroll
                    for (int c = 0; c < 16; ++c)
                        acc2[c] = pkfma(avv, wr[c], acc2[c]);
                }
            }
        }
        float4* pout = (float4*)(part + ((size_t)kchunk * 512 + img) * 128 + cc * 32);
        #pragma unroll
        for (int q = 0; q < 8; ++q)
            pout[q] = make_float4(acc2[q*2+0].x, acc2[q*2+0].y,
                                  acc2[q*2+1].x, acc2[q*2+1].y);
    }
}

// ---------------- reduce partials + b1 + relu -> x0 [512,128] ----------------
__global__ __launch_bounds__(256) void k_reduce(const float* __restrict__ part,
                                                const float* __restrict__ b1,
                                                float* __restrict__ x0) {
    int t = blockIdx.x * 256 + threadIdx.x;  // 0..65535
    float s = b1[t & 127];
    for (int ch = 0; ch < 64; ++ch)
        s += part[(size_t)ch * 65536 + t];
    x0[t] = fmaxf(s, 0.f);
}

// ---------------- fused trunk + heads (+ folded vq-loss finalize) ----------------
__device__ __forceinline__ void mlp_layer(const float in[][16], float out[][16],
                                          const float* __restrict__ W,
                                          const float* __restrict__ bias,
                                          int tid, bool dorelu) {
    const int lane = tid & 63, wv = tid >> 6;
    const int img = lane & 15, cg = lane >> 4;
    const int c0 = wv * 32 + cg * 8;
    float acc[8] = {0,0,0,0,0,0,0,0};
    for (int k = 0; k < 128; ++k) {
        float a = in[k][img];
        float4 wA = *(const float4*)(W + (size_t)k * 128 + c0);
        float4 wB = *(const float4*)(W + (size_t)k * 128 + c0 + 4);
        acc[0] = fmaf(a, wA.x, acc[0]);
        acc[1] = fmaf(a, wA.y, acc[1]);
        acc[2] = fmaf(a, wA.z, acc[2]);
        acc[3] = fmaf(a, wA.w, acc[3]);
        acc[4] = fmaf(a, wB.x, acc[4]);
        acc[5] = fmaf(a, wB.y, acc[5]);
        acc[6] = fmaf(a, wB.z, acc[6]);
        acc[7] = fmaf(a, wB.w, acc[7]);
    }
    #pragma unroll
    for (int c = 0; c < 8; ++c) {
        float v = acc[c] + bias[c0 + c];
        if (dorelu) v = fmaxf(v, 0.f);
        out[c0 + c][img] = v;
    }
}

__global__ __launch_bounds__(256) void k_trunk(const float* __restrict__ x0,
        const float* __restrict__ w2, const float* __restrict__ b2,
        const float* __restrict__ w3, const float* __restrict__ b3,
        const float* __restrict__ wa1, const float* __restrict__ ba1,
        const float* __restrict__ wa2, const float* __restrict__ ba2,
        const float* __restrict__ wc1, const float* __restrict__ bc1,
        const float* __restrict__ wc2, const float* __restrict__ bc2,
        const float* __restrict__ wc3, const float* __restrict__ bc3,
        float* __restrict__ probs, float* __restrict__ value,
        const float* __restrict__ accv, float* __restrict__ vqloss) {
    __shared__ float bufA[128][16], bufB[128][16], bufC[128][16];
    __shared__ float lg[16][10];
    const int tid = threadIdx.x;
    const int m0 = blockIdx.x * 16;
    if (blockIdx.x == 0 && tid == 0)     // folded k_vqfinal (k_vq complete: stream order)
        vqloss[0] = accv[0] * 1.25f / 33554432.f;
    for (int r = 0; r < 2; ++r) {
        int j = tid + r * 256;                 // 0..511
        int img = j >> 5, k4 = j & 31;
        float4 v = *(const float4*)(x0 + (size_t)(m0 + img) * 128 + k4 * 4);
        bufA[k4*4+0][img] = v.x;
        bufA[k4*4+1][img] = v.y;
        bufA[k4*4+2][img] = v.z;
        bufA[k4*4+3][img] = v.w;
    }
    __syncthreads();
    mlp_layer(bufA, bufB, w2, b2, tid, true);   __syncthreads();
    mlp_layer(bufB, bufC, w3, b3, tid, true);   __syncthreads();  // C = e3
    mlp_layer(bufC, bufA, wa1, ba1, tid, true); __syncthreads();  // A = a1
    if (tid < 160) {
        int img = tid & 15, col = tid >> 4;     // col 0..9
        float s = 0.f;
        for (int k = 0; k < 128; ++k)
            s = fmaf(bufA[k][img], wa2[(size_t)k * 10 + col], s);
        lg[img][col] = s + ba2[col];
    }
    __syncthreads();
    if (tid < 16) {
        int img = tid;
        float m = lg[img][0];
        #pragma unroll
        for (int c = 1; c < 10; ++c) m = fmaxf(m, lg[img][c]);
        float e[10]; float s = 0.f;
        #pragma unroll
        for (int c = 0; c < 10; ++c) { e[c] = expf(lg[img][c] - m); s += e[c]; }
        float inv = 1.f / s;
        #pragma unroll
        for (int c = 0; c < 10; ++c)
            probs[(size_t)(m0 + img) * 10 + c] = e[c] * inv;
    }
    __syncthreads();
    mlp_layer(bufC, bufB, wc1, bc1, tid, true); __syncthreads();
    mlp_layer(bufB, bufA, wc2, bc2, tid, true); __syncthreads();  // A = c2
    if (tid < 16) {
        int img = tid;
        float s = 0.f;
        for (int k = 0; k < 128; ++k)
            s = fmaf(bufA[k][img], wc3[k], s);
        value[m0 + img] = s + bc3[0];
    }
}

extern "C" void kernel_launch(void* const* d_in, const int* in_sizes, int n_in,
                              void* d_out, int out_size, void* d_ws, size_t ws_size,
                              hipStream_t stream) {
    const float* x   = (const float*)d_in[0];
    const float* c1w = (const float*)d_in[1];
    const float* c1b = (const float*)d_in[2];
    const float* c2w = (const float*)d_in[3];
    const float* c2b = (const float*)d_in[4];
    const float* cb  = (const float*)d_in[5];
    const float* w1  = (const float*)d_in[6];
    const float* b1  = (const float*)d_in[7];
    const float* w2  = (const float*)d_in[8];
    const float* b2  = (const float*)d_in[9];
    const float* w3  = (const float*)d_in[10];
    const float* b3  = (const float*)d_in[11];
    const float* wa1 = (const float*)d_in[12];
    const float* ba1 = (const float*)d_in[13];
    const float* wa2 = (const float*)d_in[14];
    const float* ba2 = (const float*)d_in[15];
    const float* wc1 = (const float*)d_in[16];
    const float* bc1 = (const float*)d_in[17];
    const float* wc2 = (const float*)d_in[18];
    const float* bc2 = (const float*)d_in[19];
    const float* wc3 = (const float*)d_in[20];
    const float* bc3 = (const float*)d_in[21];

    float* out = (float*)d_out;
    float* ws  = (float*)d_ws;

    // workspace layout (floats):
    float* h1    = ws;                                   // 16,777,216  (dead after conv2)
    float* part  = ws;                                   //  4,194,304  (reuses h1 region)
    float* x0    = ws + (size_t)4 * 1024 * 1024;         //     65,536  (inside dead h1)
    float* h     = ws + (size_t)16 * 1024 * 1024;        // 33,554,432
    int*   idxw  = (int*)(ws + (size_t)50331648);        //    524,288 ints
    float* cn    = ws + (size_t)50855936;                //        512
    float* accv  = ws + (size_t)50856448;                //          1

    hipLaunchKernelGGL(k_conv1,  dim3(512),   dim3(256), 0, stream, x, c1w, c1b, h1,
                       cb, cn, accv);
    hipLaunchKernelGGL(k_conv2,  dim3(2048),  dim3(512), 0, stream, h1, c2w, c2b, h);
    hipLaunchKernelGGL(k_vq,     dim3(4096),  dim3(512), 0, stream, h, cb, cn,
                       idxw, out + 5633, accv);
    hipLaunchKernelGGL(k_fc1,    dim3(64, 8), dim3(256), 0, stream, idxw, cb, w1, part);
    hipLaunchKernelGGL(k_reduce, dim3(256),   dim3(256), 0, stream, part, b1, x0);
    hipLaunchKernelGGL(k_trunk,  dim3(32),    dim3(256), 0, stream, x0,
                       w2, b2, w3, b3, wa1, ba1, wa2, ba2,
                       wc1, bc1, wc2, bc2, wc3, bc3,
                       out, out + 5120, accv, out + 5632);
}

// Round 5
// 974.681 us; speedup vs baseline: 2.0255x; 1.2570x over previous
//
#include <hip/hip_runtime.h>
#include <math.h>

#define NB 512
#define DD 32
#define NPX 1024      // 32*32
#define NTOT 524288   // 512*1024
#define NC 512
#define CD 64

typedef float v2f __attribute__((ext_vector_type(2)));
typedef _Float16 hf;
typedef hf hf8 __attribute__((ext_vector_type(8)));
typedef float f32x4 __attribute__((ext_vector_type(4)));

__device__ __forceinline__ v2f pkfma(v2f a, v2f b, v2f c) {
    return __builtin_elementwise_fma(a, b, c);
}
__device__ __forceinline__ v2f splat2(float s) { v2f r; r.x = s; r.y = s; return r; }

__device__ __forceinline__ f32x4 mfma16(hf8 a, hf8 b, f32x4 c) {
    return __builtin_amdgcn_mfma_f32_16x16x32_f16(a, b, c, 0, 0, 0);
}

// numpy pairwise-8 sum of squares over 64 contiguous elements.
__device__ __forceinline__ float np_sumsq64(const float* a, int stride) {
    float r[8];
    #pragma unroll
    for (int j = 0; j < 8; ++j) {
        float v = a[j * stride];
        r[j] = __fmul_rn(v, v);
    }
    #pragma unroll
    for (int i = 1; i < 8; ++i)
        #pragma unroll
        for (int j = 0; j < 8; ++j) {
            float v = a[(i * 8 + j) * stride];
            r[j] = __fadd_rn(r[j], __fmul_rn(v, v));
        }
    return __fadd_rn(__fadd_rn(__fadd_rn(r[0], r[1]), __fadd_rn(r[2], r[3])),
                     __fadd_rn(__fadd_rn(r[4], r[5]), __fadd_rn(r[6], r[7])));
}

// ---------------- conv1 (+ folded init: cnorm + loss-acc zero) ----------------
__global__ __launch_bounds__(256) void k_conv1(const float* __restrict__ x,
                                               const float* __restrict__ w,
                                               const float* __restrict__ bias,
                                               float* __restrict__ h1,
                                               const float* __restrict__ cb,
                                               float* __restrict__ cnorm,
                                               float* __restrict__ accv) {
    const int b = blockIdx.x;
    const int tid = threadIdx.x;
    {   // folded k_init: blocks 0..1 compute codebook norms; independent work
        int t = b * 256 + tid;
        if (t < NC)
            cnorm[t] = np_sumsq64(cb + (size_t)t * CD, 1);
        if (t == 0) accv[0] = 0.f;
    }
    __shared__ float xs[34][34];
    for (int i = tid; i < 34 * 34; i += 256) {
        int yy = i / 34, xx = i - yy * 34;
        float v = 0.f;
        if (yy >= 1 && yy <= 32 && xx >= 1 && xx <= 32)
            v = x[(size_t)b * NPX + (yy - 1) * 32 + (xx - 1)];
        xs[yy][xx] = v;
    }
    __syncthreads();
    for (int rep = 0; rep < 4; ++rep) {
        int px = tid + rep * 256;
        int y = px >> 5, xc = px & 31;
        v2f acc2[16];
        #pragma unroll
        for (int c = 0; c < 16; ++c) acc2[c] = splat2(0.f);
        #pragma unroll
        for (int dy = 0; dy < 3; ++dy)
        #pragma unroll
        for (int dx = 0; dx < 3; ++dx) {
            float a = xs[y + dy][xc + dx];
            v2f av = splat2(a);
            const v2f* wr = (const v2f*)(w + (dy * 3 + dx) * 32);
            #pragma unroll
            for (int c = 0; c < 16; ++c) acc2[c] = pkfma(av, wr[c], acc2[c]);
        }
        float4* out = (float4*)(h1 + ((size_t)b * NPX + px) * 32);
        #pragma unroll
        for (int q = 0; q < 8; ++q) {
            float4 v;
            v.x = fmaxf(__fadd_rn(acc2[q*2+0].x, bias[q*4+0]), 0.f);
            v.y = fmaxf(__fadd_rn(acc2[q*2+0].y, bias[q*4+1]), 0.f);
            v.z = fmaxf(__fadd_rn(acc2[q*2+1].x, bias[q*4+2]), 0.f);
            v.w = fmaxf(__fadd_rn(acc2[q*2+1].y, bias[q*4+3]), 0.f);
            out[q] = v;
        }
    }
}

// ---------------- conv2: h1 -> relu -> h [512,32,32,64], wave-co-blocked ----------------
// (R12 passing version, proven scalar form)
__global__ __launch_bounds__(512, 4) void k_conv2(const float* __restrict__ h1,
                                                  const float* __restrict__ w,
                                                  const float* __restrict__ bias,
                                                  float* __restrict__ h) {
    __shared__ float tile[32][10][34];   // 43.5 KB, [ci][row][x+1], zero-padded x
    const int blk = blockIdx.x;
    const int b = blk >> 2, strip = blk & 3;
    const int r0 = strip * 8;
    const int tid = threadIdx.x;
    for (int i = tid; i < 640; i += 512) {   // zero pad columns: 32ci x 10row x 2
        int ci = i / 20, rem = i - ci * 20;
        tile[ci][rem >> 1][(rem & 1) * 33] = 0.f;
    }
    #pragma unroll
    for (int r = 0; r < 5; ++r) {        // 2560 float4 = 10 rows x 32x x 8ci4
        int j = tid + r * 512;
        int ci4 = j & 7, xc = (j >> 3) & 31, ry = j >> 8;   // ry 0..9
        int gy = r0 - 1 + ry;
        float4 v = make_float4(0.f, 0.f, 0.f, 0.f);
        if (gy >= 0 && gy < 32)
            v = *(const float4*)(h1 + ((size_t)b * NPX + gy * 32 + xc) * 32 + ci4 * 4);
        tile[ci4 * 4 + 0][ry][xc + 1] = v.x;
        tile[ci4 * 4 + 1][ry][xc + 1] = v.y;
        tile[ci4 * 4 + 2][ry][xc + 1] = v.z;
        tile[ci4 * 4 + 3][ry][xc + 1] = v.w;
    }
    __syncthreads();
    const int lane = tid & 63;
    const int cgu = __builtin_amdgcn_readfirstlane(tid >> 6);   // wave id = co group
    const int xc = lane & 31, lrow = lane >> 5;
    float acc[4][8];
    #pragma unroll
    for (int pq = 0; pq < 4; ++pq)
        #pragma unroll
        for (int c = 0; c < 8; ++c) acc[pq][c] = 0.f;
    #pragma unroll 1
    for (int s9 = 0; s9 < 9; ++s9) {
        const int dy = s9 / 3, dx = s9 - dy * 3;
        const int xcd = xc + dx;
        #pragma unroll 1
        for (int ci0 = 0; ci0 < 32; ci0 += 4) {
            const float* wp = w + s9 * 2048 + ci0 * 64 + cgu * 8;  // uniform -> s_load
            float ws[4][8];
            #pragma unroll
            for (int i = 0; i < 4; ++i)
                #pragma unroll
                for (int c = 0; c < 8; ++c)
                    ws[i][c] = wp[i * 64 + c];
            #pragma unroll
            for (int pq = 0; pq < 4; ++pq) {
                const int row = pq * 2 + lrow + dy;
                const float a0 = tile[ci0 + 0][row][xcd];
                const float a1 = tile[ci0 + 1][row][xcd];
                const float a2 = tile[ci0 + 2][row][xcd];
                const float a3 = tile[ci0 + 3][row][xcd];
                #pragma unroll
                for (int c = 0; c < 8; ++c) {
                    acc[pq][c] = fmaf(a0, ws[0][c], acc[pq][c]);
                    acc[pq][c] = fmaf(a1, ws[1][c], acc[pq][c]);
                    acc[pq][c] = fmaf(a2, ws[2][c], acc[pq][c]);
                    acc[pq][c] = fmaf(a3, ws[3][c], acc[pq][c]);
                }
            }
        }
    }
    const float* bi = bias + cgu * 8;    // uniform -> s_load
    #pragma unroll
    for (int pq = 0; pq < 4; ++pq) {
        const int pxl = pq * 64 + lane;  // 0..255 within strip
        float* outp = h + ((size_t)b * NPX + r0 * 32 + pxl) * 64 + cgu * 8;
        float4 v0, v1;
        v0.x = fmaxf(__fadd_rn(acc[pq][0], bi[0]), 0.f);
        v0.y = fmaxf(__fadd_rn(acc[pq][1], bi[1]), 0.f);
        v0.z = fmaxf(__fadd_rn(acc[pq][2], bi[2]), 0.f);
        v0.w = fmaxf(__fadd_rn(acc[pq][3], bi[3]), 0.f);
        v1.x = fmaxf(__fadd_rn(acc[pq][4], bi[4]), 0.f);
        v1.y = fmaxf(__fadd_rn(acc[pq][5], bi[5]), 0.f);
        v1.z = fmaxf(__fadd_rn(acc[pq][6], bi[6]), 0.f);
        v1.w = fmaxf(__fadd_rn(acc[pq][7], bi[7]), 0.f);
        ((float4*)outp)[0] = v0;
        ((float4*)outp)[1] = v1;
    }
}

// ---------------- k_prep: split codebook into scaled f16 hi/lo ----------------
// b' = 256*b; bh = f16(b'); bl = f16((b'-bh)*2048).
// dot reconstructed as (hi + lo/2048 + ll/2^22)/65536.
__global__ __launch_bounds__(256) void k_prep(const float* __restrict__ cb,
                                              hf* __restrict__ cbh,
                                              hf* __restrict__ cbl) {
    int t = blockIdx.x * 256 + threadIdx.x;  // 0..32767
    float a = cb[t] * 256.f;
    hf h0 = (hf)a;
    float rl = (a - (float)h0) * 2048.f;
    cbh[t] = h0;
    cbl[t] = (hf)rl;
}

// ---------------- VQ: 3-term split-f16 MFMA screener + certified exact rescue ----------------
// Approx d error bound B ~ 7e-6; gap > TAU=1e-3 >> 2B certifies the approx winner
// equals the exact-fp32 winner. Gap <= TAU -> block-wide exact recompute (bit-identical
// R0 fmaf chain, lexicographic (v,idx) = numpy first-occurrence).
#define TAU 1e-3f
__global__ __launch_bounds__(256, 3) void k_vq(const float* __restrict__ h,
                                               const float* __restrict__ cb,
                                               const hf* __restrict__ cbh,
                                               const hf* __restrict__ cbl,
                                               const float* __restrict__ cnorm,
                                               int* __restrict__ idxout,
                                               float* __restrict__ fidx,
                                               float* __restrict__ lossacc) {
    __shared__ float4 Ats[16][128];   // 32 KB: [kgroup][px] = h[base+px][4kg..4kg+3]
    __shared__ float Hs[128];
    __shared__ float cn_lds[512];
    __shared__ int   mis_lds[128];
    __shared__ float r_v[256];
    __shared__ int   r_i[256];
    __shared__ int   rlist[128];
    __shared__ int   rcnt;
    const int tid = threadIdx.x;
    const size_t base = (size_t)blockIdx.x * 128;
    if (tid == 0) rcnt = 0;
    {   // stage h rows
        const int px = tid & 127, half = tid >> 7;
        const float4* src = (const float4*)(h + (base + px) * 64 + half * 32);
        #pragma unroll
        for (int j = 0; j < 8; ++j)
            Ats[half * 8 + j][px] = src[j];
    }
    for (int i = tid; i < 512; i += 256) cn_lds[i] = cnorm[i];
    __syncthreads();
    if (tid < 128) {   // numpy pairwise-8 ||h||^2 for pixel tid (bit-identical to R0)
        float f[64];
        #pragma unroll
        for (int kg = 0; kg < 16; ++kg) {
            float4 v = Ats[kg][tid];
            f[kg*4+0] = v.x; f[kg*4+1] = v.y; f[kg*4+2] = v.z; f[kg*4+3] = v.w;
        }
        float r[8];
        #pragma unroll
        for (int j = 0; j < 8; ++j) r[j] = __fmul_rn(f[j], f[j]);
        #pragma unroll
        for (int i = 1; i < 8; ++i)
            #pragma unroll
            for (int j = 0; j < 8; ++j)
                r[j] = __fadd_rn(r[j], __fmul_rn(f[i*8+j], f[i*8+j]));
        Hs[tid] = __fadd_rn(__fadd_rn(__fadd_rn(r[0], r[1]), __fadd_rn(r[2], r[3])),
                            __fadd_rn(__fadd_rn(r[4], r[5]), __fadd_rn(r[6], r[7])));
    }
    __syncthreads();
    const int w = tid >> 6, l = tid & 63;
    const int co = l & 15, g = l >> 4;     // co: code lane idx; g: k-group / px-row group
    const int pxw = w * 32;                // this wave's 32-px strip (2 M-subtiles)
    // A fragments (f16 3-way usable split): [subtile][kstep]
    hf8 ah[2][2], al[2][2];
    #pragma unroll
    for (int s = 0; s < 2; ++s)
        #pragma unroll
        for (int ks = 0; ks < 2; ++ks) {
            float4 q0 = Ats[ks * 8 + g * 2 + 0][pxw + s * 16 + co];
            float4 q1 = Ats[ks * 8 + g * 2 + 1][pxw + s * 16 + co];
            float fv[8] = {q0.x, q0.y, q0.z, q0.w, q1.x, q1.y, q1.z, q1.w};
            #pragma unroll
            for (int j = 0; j < 8; ++j) {
                float fa = fv[j] * 256.f;               // exact pow2 scale
                hf h0 = (hf)fa;
                float rl = (fa - (float)h0) * 2048.f;   // exact (Sterbenz + pow2)
                ah[s][ks][j] = h0;
                al[s][ks][j] = (hf)rl;
            }
        }
    float Hr[2][4];
    #pragma unroll
    for (int s = 0; s < 2; ++s)
        #pragma unroll
        for (int r = 0; r < 4; ++r)
            Hr[s][r] = Hs[pxw + s * 16 + g * 4 + r];
    float minv[2][4], min2[2][4];
    int   mini[2][4];
    #pragma unroll
    for (int s = 0; s < 2; ++s)
        #pragma unroll
        for (int r = 0; r < 4; ++r) {
            minv[s][r] = 3.4e38f; min2[s][r] = 3.4e38f; mini[s][r] = 0;
        }
    const hf* pbh = cbh + (size_t)co * 64 + g * 8;
    const hf* pbl = cbl + (size_t)co * 64 + g * 8;
    #pragma unroll 1
    for (int t = 0; t < 32; ++t) {          // 32 code tiles x 16 codes, ascending
        const hf8 bh0 = *(const hf8*)(pbh + (size_t)t * 1024);
        const hf8 bh1 = *(const hf8*)(pbh + (size_t)t * 1024 + 32);
        const hf8 bl0 = *(const hf8*)(pbl + (size_t)t * 1024);
        const hf8 bl1 = *(const hf8*)(pbl + (size_t)t * 1024 + 32);
        const float cn = cn_lds[t * 16 + co];
        #pragma unroll
        for (int s = 0; s < 2; ++s) {
            f32x4 hi = {0.f, 0.f, 0.f, 0.f};
            f32x4 lo = {0.f, 0.f, 0.f, 0.f};
            f32x4 ll = {0.f, 0.f, 0.f, 0.f};
            lo = mfma16(ah[s][0], bl0, lo);
            lo = mfma16(al[s][0], bh0, lo);
            ll = mfma16(al[s][0], bl0, ll);
            hi = mfma16(ah[s][0], bh0, hi);
            lo = mfma16(ah[s][1], bl1, lo);
            lo = mfma16(al[s][1], bh1, lo);
            ll = mfma16(al[s][1], bl1, ll);
            hi = mfma16(ah[s][1], bh1, hi);
            #pragma unroll
            for (int r = 0; r < 4; ++r) {
                float comb = fmaf(lo[r], 4.8828125e-4f,
                             fmaf(ll[r], 2.384185791015625e-7f, hi[r]));
                float d = __fadd_rn(__fsub_rn(Hr[s][r],
                              __fmul_rn(3.0517578125e-5f, comb)), cn);  // 2/65536
                if (d < minv[s][r]) {
                    min2[s][r] = minv[s][r];
                    minv[s][r] = d; mini[s][r] = t * 16 + co;
                } else if (d < min2[s][r]) {
                    min2[s][r] = d;
                }
            }
        }
    }
    // cross-lane top-2 merge over the 16 code-lanes (tie -> lower index)
    #pragma unroll
    for (int s = 0; s < 2; ++s)
        #pragma unroll
        for (int r = 0; r < 4; ++r) {
            float v1 = minv[s][r], v2 = min2[s][r];
            int i1 = mini[s][r];
            #pragma unroll
            for (int off = 1; off < 16; off <<= 1) {
                float vo  = __shfl_xor(v1, off, 64);
                int   io  = __shfl_xor(i1, off, 64);
                float v2o = __shfl_xor(v2, off, 64);
                if (vo < v1 || (vo == v1 && io < i1)) {
                    v2 = fminf(v1, v2o);
                    v1 = vo; i1 = io;
                } else {
                    v2 = fminf(v2, vo);
                }
            }
            if (co == 0) {
                int pxo = pxw + s * 16 + g * 4 + r;
                mis_lds[pxo] = i1;
                if (v2 - v1 <= TAU) {
                    int slot = atomicAdd(&rcnt, 1);
                    rlist[slot] = pxo;
                }
            }
        }
    __syncthreads();
    // ---- certified exact rescue (rare): full 512-code fp32 recompute, R0 chain ----
    const int nresc = rcnt;
    for (int rr = 0; rr < nresc; ++rr) {
        const int px = rlist[rr];
        const float Hp = Hs[px];
        const int c0 = tid * 2;
        float acc0 = 0.f, acc1 = 0.f;
        const float* crow0 = cb + (size_t)c0 * 64;
        const float* crow1 = crow0 + 64;
        #pragma unroll
        for (int kg = 0; kg < 16; ++kg) {
            float4 a = Ats[kg][px];
            acc0 = fmaf(a.x, crow0[kg*4+0], acc0);
            acc0 = fmaf(a.y, crow0[kg*4+1], acc0);
            acc0 = fmaf(a.z, crow0[kg*4+2], acc0);
            acc0 = fmaf(a.w, crow0[kg*4+3], acc0);
            acc1 = fmaf(a.x, crow1[kg*4+0], acc1);
            acc1 = fmaf(a.y, crow1[kg*4+1], acc1);
            acc1 = fmaf(a.z, crow1[kg*4+2], acc1);
            acc1 = fmaf(a.w, crow1[kg*4+3], acc1);
        }
        float d0 = __fadd_rn(__fsub_rn(Hp, __fmul_rn(2.f, acc0)), cn_lds[c0]);
        float d1 = __fadd_rn(__fsub_rn(Hp, __fmul_rn(2.f, acc1)), cn_lds[c0 + 1]);
        float bv = d0; int bi = c0;
        if (d1 < bv) { bv = d1; bi = c0 + 1; }
        r_v[tid] = bv; r_i[tid] = bi;
        __syncthreads();
        for (int st = 128; st > 0; st >>= 1) {
            if (tid < st) {
                float vo = r_v[tid + st]; int io = r_i[tid + st];
                if (vo < r_v[tid] || (vo == r_v[tid] && io < r_i[tid])) {
                    r_v[tid] = vo; r_i[tid] = io;
                }
            }
            __syncthreads();
        }
        if (tid == 0) mis_lds[px] = r_i[0];
        __syncthreads();
    }
    // ---- outputs + loss epilogue (exact fp32, same chain order as R0) ----
    if (tid < 128) {
        int bi = mis_lds[tid];
        idxout[base + tid] = bi;
        fidx[base + tid] = (float)bi;
        float ls = 0.f;
        const float* crow = cb + (size_t)bi * 64;
        #pragma unroll
        for (int kg = 0; kg < 16; ++kg) {
            float4 a = Ats[kg][tid];
            float d0 = crow[kg*4+0] - a.x;
            float d1 = crow[kg*4+1] - a.y;
            float d2 = crow[kg*4+2] - a.z;
            float d3 = crow[kg*4+3] - a.w;
            ls = fmaf(d0, d0, ls); ls = fmaf(d1, d1, ls);
            ls = fmaf(d2, d2, ls); ls = fmaf(d3, d3, ls);
        }
        #pragma unroll
        for (int off = 32; off > 0; off >>= 1)
            ls += __shfl_down(ls, off, 64);
        if ((tid & 63) == 0) atomicAdd(lossacc, ls);
    }
}

// ---------------- fc1: emb[512,65536] @ w1[65536,128], K-split partials ----------------
__global__ __launch_bounds__(256) void k_fc1(const int* __restrict__ idxw,
                                             const float* __restrict__ cb,
                                             const float* __restrict__ w1,
                                             float* __restrict__ part) {
    const int kchunk = blockIdx.x;       // 0..63  (16 pixels each)
    const int mtile  = blockIdx.y;       // 0..7   (64 images each)
    const int tid = threadIdx.x;
    const int wv = tid >> 6, lane = tid & 63;
    const int img = mtile * 64 + lane;
    const int pbase = kchunk * 16 + wv * 4;
    const int pbu = __builtin_amdgcn_readfirstlane(pbase);  // force uniform for s_loads
    int code[4];
    #pragma unroll
    for (int pp = 0; pp < 4; ++pp)
        code[pp] = idxw[(size_t)img * NPX + pbase + pp];
    for (int cc = 0; cc < 4; ++cc) {
        v2f acc2[16];
        #pragma unroll
        for (int c = 0; c < 16; ++c) acc2[c] = splat2(0.f);
        #pragma unroll
        for (int pp = 0; pp < 4; ++pp) {
            const float* arow = cb + (size_t)code[pp] * 64;
            const float* wrow = w1 + ((size_t)(pbu + pp) * 64) * 128 + cc * 32;
            for (int kc = 0; kc < 4; ++kc) {
                float4 a4[4];
                #pragma unroll
                for (int q = 0; q < 4; ++q)
                    a4[q] = *(const float4*)(arow + kc * 16 + q * 4);
                #pragma unroll
                for (int kk = 0; kk < 16; ++kk) {
                    float av = ((const float*)a4)[kk];
                    v2f avv = splat2(av);
                    const v2f* wr = (const v2f*)(wrow + (size_t)(kc * 16 + kk) * 128);
                    #pragma unroll
                    for (int c = 0; c < 16; ++c)
                        acc2[c] = pkfma(avv, wr[c], acc2[c]);
                }
            }
        }
        float4* pout = (float4*)(part + ((size_t)kchunk * 512 + img) * 128 + cc * 32);
        #pragma unroll
        for (int q = 0; q < 8; ++q)
            pout[q] = make_float4(acc2[q*2+0].x, acc2[q*2+0].y,
                                  acc2[q*2+1].x, acc2[q*2+1].y);
    }
}

// ---------------- reduce partials + b1 + relu -> x0 [512,128] ----------------
__global__ __launch_bounds__(256) void k_reduce(const float* __restrict__ part,
                                                const float* __restrict__ b1,
                                                float* __restrict__ x0) {
    int t = blockIdx.x * 256 + threadIdx.x;  // 0..65535
    float s = b1[t & 127];
    for (int ch = 0; ch < 64; ++ch)
        s += part[(size_t)ch * 65536 + t];
    x0[t] = fmaxf(s, 0.f);
}

// ---------------- fused trunk + heads (+ folded vq-loss finalize) ----------------
__device__ __forceinline__ void mlp_layer(const float in[][16], float out[][16],
                                          const float* __restrict__ W,
                                          const float* __restrict__ bias,
                                          int tid, bool dorelu) {
    const int lane = tid & 63, wv = tid >> 6;
    const int img = lane & 15, cg = lane >> 4;
    const int c0 = wv * 32 + cg * 8;
    float acc[8] = {0,0,0,0,0,0,0,0};
    for (int k = 0; k < 128; ++k) {
        float a = in[k][img];
        float4 wA = *(const float4*)(W + (size_t)k * 128 + c0);
        float4 wB = *(const float4*)(W + (size_t)k * 128 + c0 + 4);
        acc[0] = fmaf(a, wA.x, acc[0]);
        acc[1] = fmaf(a, wA.y, acc[1]);
        acc[2] = fmaf(a, wA.z, acc[2]);
        acc[3] = fmaf(a, wA.w, acc[3]);
        acc[4] = fmaf(a, wB.x, acc[4]);
        acc[5] = fmaf(a, wB.y, acc[5]);
        acc[6] = fmaf(a, wB.z, acc[6]);
        acc[7] = fmaf(a, wB.w, acc[7]);
    }
    #pragma unroll
    for (int c = 0; c < 8; ++c) {
        float v = acc[c] + bias[c0 + c];
        if (dorelu) v = fmaxf(v, 0.f);
        out[c0 + c][img] = v;
    }
}

__global__ __launch_bounds__(256) void k_trunk(const float* __restrict__ x0,
        const float* __restrict__ w2, const float* __restrict__ b2,
        const float* __restrict__ w3, const float* __restrict__ b3,
        const float* __restrict__ wa1, const float* __restrict__ ba1,
        const float* __restrict__ wa2, const float* __restrict__ ba2,
        const float* __restrict__ wc1, const float* __restrict__ bc1,
        const float* __restrict__ wc2, const float* __restrict__ bc2,
        const float* __restrict__ wc3, const float* __restrict__ bc3,
        float* __restrict__ probs, float* __restrict__ value,
        const float* __restrict__ accv, float* __restrict__ vqloss) {
    __shared__ float bufA[128][16], bufB[128][16], bufC[128][16];
    __shared__ float lg[16][10];
    const int tid = threadIdx.x;
    const int m0 = blockIdx.x * 16;
    if (blockIdx.x == 0 && tid == 0)     // folded k_vqfinal (k_vq complete: stream order)
        vqloss[0] = accv[0] * 1.25f / 33554432.f;
    for (int r = 0; r < 2; ++r) {
        int j = tid + r * 256;                 // 0..511
        int img = j >> 5, k4 = j & 31;
        float4 v = *(const float4*)(x0 + (size_t)(m0 + img) * 128 + k4 * 4);
        bufA[k4*4+0][img] = v.x;
        bufA[k4*4+1][img] = v.y;
        bufA[k4*4+2][img] = v.z;
        bufA[k4*4+3][img] = v.w;
    }
    __syncthreads();
    mlp_layer(bufA, bufB, w2, b2, tid, true);   __syncthreads();
    mlp_layer(bufB, bufC, w3, b3, tid, true);   __syncthreads();  // C = e3
    mlp_layer(bufC, bufA, wa1, ba1, tid, true); __syncthreads();  // A = a1
    if (tid < 160) {
        int img = tid & 15, col = tid >> 4;     // col 0..9
        float s = 0.f;
        for (int k = 0; k < 128; ++k)
            s = fmaf(bufA[k][img], wa2[(size_t)k * 10 + col], s);
        lg[img][col] = s + ba2[col];
    }
    __syncthreads();
    if (tid < 16) {
        int img = tid;
        float m = lg[img][0];
        #pragma unroll
        for (int c = 1; c < 10; ++c) m = fmaxf(m, lg[img][c]);
        float e[10]; float s = 0.f;
        #pragma unroll
        for (int c = 0; c < 10; ++c) { e[c] = expf(lg[img][c] - m); s += e[c]; }
        float inv = 1.f / s;
        #pragma unroll
        for (int c = 0; c < 10; ++c)
            probs[(size_t)(m0 + img) * 10 + c] = e[c] * inv;
    }
    __syncthreads();
    mlp_layer(bufC, bufB, wc1, bc1, tid, true); __syncthreads();
    mlp_layer(bufB, bufA, wc2, bc2, tid, true); __syncthreads();  // A = c2
    if (tid < 16) {
        int img = tid;
        float s = 0.f;
        for (int k = 0; k < 128; ++k)
            s = fmaf(bufA[k][img], wc3[k], s);
        value[m0 + img] = s + bc3[0];
    }
}

extern "C" void kernel_launch(void* const* d_in, const int* in_sizes, int n_in,
                              void* d_out, int out_size, void* d_ws, size_t ws_size,
                              hipStream_t stream) {
    const float* x   = (const float*)d_in[0];
    const float* c1w = (const float*)d_in[1];
    const float* c1b = (const float*)d_in[2];
    const float* c2w = (const float*)d_in[3];
    const float* c2b = (const float*)d_in[4];
    const float* cb  = (const float*)d_in[5];
    const float* w1  = (const float*)d_in[6];
    const float* b1  = (const float*)d_in[7];
    const float* w2  = (const float*)d_in[8];
    const float* b2  = (const float*)d_in[9];
    const float* w3  = (const float*)d_in[10];
    const float* b3  = (const float*)d_in[11];
    const float* wa1 = (const float*)d_in[12];
    const float* ba1 = (const float*)d_in[13];
    const float* wa2 = (const float*)d_in[14];
    const float* ba2 = (const float*)d_in[15];
    const float* wc1 = (const float*)d_in[16];
    const float* bc1 = (const float*)d_in[17];
    const float* wc2 = (const float*)d_in[18];
    const float* bc2 = (const float*)d_in[19];
    const float* wc3 = (const float*)d_in[20];
    const float* bc3 = (const float*)d_in[21];

    float* out = (float*)d_out;
    float* ws  = (float*)d_ws;

    // workspace layout (floats):
    float* h1    = ws;                                   // 16,777,216  (dead after conv2)
    float* part  = ws;                                   //  4,194,304  (reuses h1 region)
    float* x0    = ws + (size_t)4 * 1024 * 1024;         //     65,536  (inside dead h1)
    hf*    cbh   = (hf*)(ws + (size_t)8388608);          //     32,768 f16 (dead-h1 region,
    hf*    cbl   = (hf*)(ws + (size_t)8404992);          //     32,768 f16  written post-conv2)
    float* h     = ws + (size_t)16 * 1024 * 1024;        // 33,554,432
    int*   idxw  = (int*)(ws + (size_t)50331648);        //    524,288 ints
    float* cn    = ws + (size_t)50855936;                //        512
    float* accv  = ws + (size_t)50856448;                //          1

    hipLaunchKernelGGL(k_conv1,  dim3(512),   dim3(256), 0, stream, x, c1w, c1b, h1,
                       cb, cn, accv);
    hipLaunchKernelGGL(k_conv2,  dim3(2048),  dim3(512), 0, stream, h1, c2w, c2b, h);
    hipLaunchKernelGGL(k_prep,   dim3(128),   dim3(256), 0, stream, cb, cbh, cbl);
    hipLaunchKernelGGL(k_vq,     dim3(4096),  dim3(256), 0, stream, h, cb, cbh, cbl, cn,
                       idxw, out + 5633, accv);
    hipLaunchKernelGGL(k_fc1,    dim3(64, 8), dim3(256), 0, stream, idxw, cb, w1, part);
    hipLaunchKernelGGL(k_reduce, dim3(256),   dim3(256), 0, stream, part, b1, x0);
    hipLaunchKernelGGL(k_trunk,  dim3(32),    dim3(256), 0, stream, x0,
                       w2, b2, w3, b3, wa1, ba1, wa2, ba2,
                       wc1, bc1, wc2, bc2, wc3, bc3,
                       out, out + 5120, accv, out + 5632);
}

// Round 6
// 970.684 us; speedup vs baseline: 2.0339x; 1.0041x over previous
//
#include <hip/hip_runtime.h>
#include <math.h>

#define NB 512
#define DD 32
#define NPX 1024      // 32*32
#define NTOT 524288   // 512*1024
#define NC 512
#define CD 64

typedef float v2f __attribute__((ext_vector_type(2)));
typedef _Float16 hf;
typedef hf hf8 __attribute__((ext_vector_type(8)));
typedef float f32x4 __attribute__((ext_vector_type(4)));

__device__ __forceinline__ v2f pkfma(v2f a, v2f b, v2f c) {
    return __builtin_elementwise_fma(a, b, c);
}
__device__ __forceinline__ v2f splat2(float s) { v2f r; r.x = s; r.y = s; return r; }

__device__ __forceinline__ f32x4 mfma16(hf8 a, hf8 b, f32x4 c) {
    return __builtin_amdgcn_mfma_f32_16x16x32_f16(a, b, c, 0, 0, 0);
}

// numpy pairwise-8 sum of squares over 64 contiguous elements.
__device__ __forceinline__ float np_sumsq64(const float* a, int stride) {
    float r[8];
    #pragma unroll
    for (int j = 0; j < 8; ++j) {
        float v = a[j * stride];
        r[j] = __fmul_rn(v, v);
    }
    #pragma unroll
    for (int i = 1; i < 8; ++i)
        #pragma unroll
        for (int j = 0; j < 8; ++j) {
            float v = a[(i * 8 + j) * stride];
            r[j] = __fadd_rn(r[j], __fmul_rn(v, v));
        }
    return __fadd_rn(__fadd_rn(__fadd_rn(r[0], r[1]), __fadd_rn(r[2], r[3])),
                     __fadd_rn(__fadd_rn(r[4], r[5]), __fadd_rn(r[6], r[7])));
}

// ---------------- conv1 (+ folded init: cnorm, f16-split prep, loss-acc zero) ----------------
__global__ __launch_bounds__(256) void k_conv1(const float* __restrict__ x,
                                               const float* __restrict__ w,
                                               const float* __restrict__ bias,
                                               float* __restrict__ h1,
                                               const float* __restrict__ cb,
                                               float* __restrict__ cnorm,
                                               hf* __restrict__ cbh,
                                               hf* __restrict__ cbl,
                                               float* __restrict__ accv) {
    const int b = blockIdx.x;
    const int tid = threadIdx.x;
    {   // folded k_init + k_prep: independent side work on low blocks
        int t = b * 256 + tid;
        if (t < NC)
            cnorm[t] = np_sumsq64(cb + (size_t)t * CD, 1);
        if (b < 128) {   // t < 32768: split codebook into scaled f16 hi/lo
            float a = cb[t] * 256.f;             // exact pow2 scale
            hf h0 = (hf)a;
            float rl = (a - (float)h0) * 2048.f; // exact (Sterbenz + pow2)
            cbh[t] = h0;
            cbl[t] = (hf)rl;
        }
        if (t == 0) accv[0] = 0.f;
    }
    __shared__ float xs[34][34];
    for (int i = tid; i < 34 * 34; i += 256) {
        int yy = i / 34, xx = i - yy * 34;
        float v = 0.f;
        if (yy >= 1 && yy <= 32 && xx >= 1 && xx <= 32)
            v = x[(size_t)b * NPX + (yy - 1) * 32 + (xx - 1)];
        xs[yy][xx] = v;
    }
    __syncthreads();
    for (int rep = 0; rep < 4; ++rep) {
        int px = tid + rep * 256;
        int y = px >> 5, xc = px & 31;
        v2f acc2[16];
        #pragma unroll
        for (int c = 0; c < 16; ++c) acc2[c] = splat2(0.f);
        #pragma unroll
        for (int dy = 0; dy < 3; ++dy)
        #pragma unroll
        for (int dx = 0; dx < 3; ++dx) {
            float a = xs[y + dy][xc + dx];
            v2f av = splat2(a);
            const v2f* wr = (const v2f*)(w + (dy * 3 + dx) * 32);
            #pragma unroll
            for (int c = 0; c < 16; ++c) acc2[c] = pkfma(av, wr[c], acc2[c]);
        }
        float4* out = (float4*)(h1 + ((size_t)b * NPX + px) * 32);
        #pragma unroll
        for (int q = 0; q < 8; ++q) {
            float4 v;
            v.x = fmaxf(__fadd_rn(acc2[q*2+0].x, bias[q*4+0]), 0.f);
            v.y = fmaxf(__fadd_rn(acc2[q*2+0].y, bias[q*4+1]), 0.f);
            v.z = fmaxf(__fadd_rn(acc2[q*2+1].x, bias[q*4+2]), 0.f);
            v.w = fmaxf(__fadd_rn(acc2[q*2+1].y, bias[q*4+3]), 0.f);
            out[q] = v;
        }
    }
}

// ---------------- conv2: h1 -> relu -> h [512,32,32,64], wave-co-blocked ----------------
// (R12 passing version, proven scalar form)
__global__ __launch_bounds__(512, 4) void k_conv2(const float* __restrict__ h1,
                                                  const float* __restrict__ w,
                                                  const float* __restrict__ bias,
                                                  float* __restrict__ h) {
    __shared__ float tile[32][10][34];   // 43.5 KB, [ci][row][x+1], zero-padded x
    const int blk = blockIdx.x;
    const int b = blk >> 2, strip = blk & 3;
    const int r0 = strip * 8;
    const int tid = threadIdx.x;
    for (int i = tid; i < 640; i += 512) {   // zero pad columns: 32ci x 10row x 2
        int ci = i / 20, rem = i - ci * 20;
        tile[ci][rem >> 1][(rem & 1) * 33] = 0.f;
    }
    #pragma unroll
    for (int r = 0; r < 5; ++r) {        // 2560 float4 = 10 rows x 32x x 8ci4
        int j = tid + r * 512;
        int ci4 = j & 7, xc = (j >> 3) & 31, ry = j >> 8;   // ry 0..9
        int gy = r0 - 1 + ry;
        float4 v = make_float4(0.f, 0.f, 0.f, 0.f);
        if (gy >= 0 && gy < 32)
            v = *(const float4*)(h1 + ((size_t)b * NPX + gy * 32 + xc) * 32 + ci4 * 4);
        tile[ci4 * 4 + 0][ry][xc + 1] = v.x;
        tile[ci4 * 4 + 1][ry][xc + 1] = v.y;
        tile[ci4 * 4 + 2][ry][xc + 1] = v.z;
        tile[ci4 * 4 + 3][ry][xc + 1] = v.w;
    }
    __syncthreads();
    const int lane = tid & 63;
    const int cgu = __builtin_amdgcn_readfirstlane(tid >> 6);   // wave id = co group
    const int xc = lane & 31, lrow = lane >> 5;
    float acc[4][8];
    #pragma unroll
    for (int pq = 0; pq < 4; ++pq)
        #pragma unroll
        for (int c = 0; c < 8; ++c) acc[pq][c] = 0.f;
    #pragma unroll 1
    for (int s9 = 0; s9 < 9; ++s9) {
        const int dy = s9 / 3, dx = s9 - dy * 3;
        const int xcd = xc + dx;
        #pragma unroll 1
        for (int ci0 = 0; ci0 < 32; ci0 += 4) {
            const float* wp = w + s9 * 2048 + ci0 * 64 + cgu * 8;  // uniform -> s_load
            float ws[4][8];
            #pragma unroll
            for (int i = 0; i < 4; ++i)
                #pragma unroll
                for (int c = 0; c < 8; ++c)
                    ws[i][c] = wp[i * 64 + c];
            #pragma unroll
            for (int pq = 0; pq < 4; ++pq) {
                const int row = pq * 2 + lrow + dy;
                const float a0 = tile[ci0 + 0][row][xcd];
                const float a1 = tile[ci0 + 1][row][xcd];
                const float a2 = tile[ci0 + 2][row][xcd];
                const float a3 = tile[ci0 + 3][row][xcd];
                #pragma unroll
                for (int c = 0; c < 8; ++c) {
                    acc[pq][c] = fmaf(a0, ws[0][c], acc[pq][c]);
                    acc[pq][c] = fmaf(a1, ws[1][c], acc[pq][c]);
                    acc[pq][c] = fmaf(a2, ws[2][c], acc[pq][c]);
                    acc[pq][c] = fmaf(a3, ws[3][c], acc[pq][c]);
                }
            }
        }
    }
    const float* bi = bias + cgu * 8;    // uniform -> s_load
    #pragma unroll
    for (int pq = 0; pq < 4; ++pq) {
        const int pxl = pq * 64 + lane;  // 0..255 within strip
        float* outp = h + ((size_t)b * NPX + r0 * 32 + pxl) * 64 + cgu * 8;
        float4 v0, v1;
        v0.x = fmaxf(__fadd_rn(acc[pq][0], bi[0]), 0.f);
        v0.y = fmaxf(__fadd_rn(acc[pq][1], bi[1]), 0.f);
        v0.z = fmaxf(__fadd_rn(acc[pq][2], bi[2]), 0.f);
        v0.w = fmaxf(__fadd_rn(acc[pq][3], bi[3]), 0.f);
        v1.x = fmaxf(__fadd_rn(acc[pq][4], bi[4]), 0.f);
        v1.y = fmaxf(__fadd_rn(acc[pq][5], bi[5]), 0.f);
        v1.z = fmaxf(__fadd_rn(acc[pq][6], bi[6]), 0.f);
        v1.w = fmaxf(__fadd_rn(acc[pq][7], bi[7]), 0.f);
        ((float4*)outp)[0] = v0;
        ((float4*)outp)[1] = v1;
    }
}

// ---------------- VQ: 2-term split-f16 MFMA screener + certified exact rescue ----------------
// Screener d error bound B ~ 5e-6 (dropped al*bl term <= sqrt(H*cn)*2^-22 ~ 2e-6, plus
// split roundings); gap > TAU=1e-3 >> 2B certifies the approx winner equals the exact
// fp32 winner. Gap <= TAU -> block-wide exact recompute (bit-identical R0 fmaf chain,
// lexicographic (v,idx) = numpy first-occurrence).  B-operand loads are software-
// pipelined (ping-pong, issued one tile ahead) to hide L1/L2 latency.
#define TAU 1e-3f
#define VQTILE(tt, xh0, xh1, xl0, xl1)                                              \
    do {                                                                            \
        const float cn_ = cn_lds[(tt) * 16 + co];                                   \
        _Pragma("unroll")                                                           \
        for (int s = 0; s < 2; ++s) {                                               \
            f32x4 hi = {0.f, 0.f, 0.f, 0.f};                                        \
            f32x4 lo = {0.f, 0.f, 0.f, 0.f};                                        \
            lo = mfma16(ah[s][0], xl0, lo);                                         \
            lo = mfma16(al[s][0], xh0, lo);                                         \
            hi = mfma16(ah[s][0], xh0, hi);                                         \
            lo = mfma16(ah[s][1], xl1, lo);                                         \
            lo = mfma16(al[s][1], xh1, lo);                                         \
            hi = mfma16(ah[s][1], xh1, hi);                                         \
            _Pragma("unroll")                                                       \
            for (int r = 0; r < 4; ++r) {                                           \
                float comb = fmaf(lo[r], 4.8828125e-4f, hi[r]);                     \
                float d = __fadd_rn(__fsub_rn(Hr[s][r],                             \
                              __fmul_rn(3.0517578125e-5f, comb)), cn_);             \
                if (d < minv[s][r]) {                                               \
                    min2[s][r] = minv[s][r];                                        \
                    minv[s][r] = d; mini[s][r] = (tt) * 16 + co;                    \
                } else if (d < min2[s][r]) {                                        \
                    min2[s][r] = d;                                                 \
                }                                                                   \
            }                                                                       \
        }                                                                           \
    } while (0)

__global__ __launch_bounds__(256, 4) void k_vq(const float* __restrict__ h,
                                               const float* __restrict__ cb,
                                               const hf* __restrict__ cbh,
                                               const hf* __restrict__ cbl,
                                               const float* __restrict__ cnorm,
                                               int* __restrict__ idxout,
                                               float* __restrict__ fidx,
                                               float* __restrict__ lossacc) {
    __shared__ float4 Ats[16][128];   // 32 KB: [kgroup][px] = h[base+px][4kg..4kg+3]
    __shared__ float Hs[128];
    __shared__ float cn_lds[512];
    __shared__ int   mis_lds[128];
    __shared__ float r_v[256];
    __shared__ int   r_i[256];
    __shared__ int   rlist[128];
    __shared__ int   rcnt;
    const int tid = threadIdx.x;
    const size_t base = (size_t)blockIdx.x * 128;
    if (tid == 0) rcnt = 0;
    {   // stage h rows
        const int px = tid & 127, half = tid >> 7;
        const float4* src = (const float4*)(h + (base + px) * 64 + half * 32);
        #pragma unroll
        for (int j = 0; j < 8; ++j)
            Ats[half * 8 + j][px] = src[j];
    }
    for (int i = tid; i < 512; i += 256) cn_lds[i] = cnorm[i];
    __syncthreads();
    if (tid < 128) {   // numpy pairwise-8 ||h||^2 for pixel tid (bit-identical to R0)
        float f[64];
        #pragma unroll
        for (int kg = 0; kg < 16; ++kg) {
            float4 v = Ats[kg][tid];
            f[kg*4+0] = v.x; f[kg*4+1] = v.y; f[kg*4+2] = v.z; f[kg*4+3] = v.w;
        }
        float r[8];
        #pragma unroll
        for (int j = 0; j < 8; ++j) r[j] = __fmul_rn(f[j], f[j]);
        #pragma unroll
        for (int i = 1; i < 8; ++i)
            #pragma unroll
            for (int j = 0; j < 8; ++j)
                r[j] = __fadd_rn(r[j], __fmul_rn(f[i*8+j], f[i*8+j]));
        Hs[tid] = __fadd_rn(__fadd_rn(__fadd_rn(r[0], r[1]), __fadd_rn(r[2], r[3])),
                            __fadd_rn(__fadd_rn(r[4], r[5]), __fadd_rn(r[6], r[7])));
    }
    __syncthreads();
    const int w = tid >> 6, l = tid & 63;
    const int co = l & 15, g = l >> 4;     // co: code lane idx; g: k-group / px-row group
    const int pxw = w * 32;                // this wave's 32-px strip (2 M-subtiles)
    // A fragments (f16 split): [subtile][kstep], 8 contiguous k per lane
    hf8 ah[2][2], al[2][2];
    #pragma unroll
    for (int s = 0; s < 2; ++s)
        #pragma unroll
        for (int ks = 0; ks < 2; ++ks) {
            float4 q0 = Ats[ks * 8 + g * 2 + 0][pxw + s * 16 + co];
            float4 q1 = Ats[ks * 8 + g * 2 + 1][pxw + s * 16 + co];
            float fv[8] = {q0.x, q0.y, q0.z, q0.w, q1.x, q1.y, q1.z, q1.w};
            #pragma unroll
            for (int j = 0; j < 8; ++j) {
                float fa = fv[j] * 256.f;               // exact pow2 scale
                hf h0 = (hf)fa;
                float rl = (fa - (float)h0) * 2048.f;   // exact (Sterbenz + pow2)
                ah[s][ks][j] = h0;
                al[s][ks][j] = (hf)rl;
            }
        }
    float Hr[2][4];
    #pragma unroll
    for (int s = 0; s < 2; ++s)
        #pragma unroll
        for (int r = 0; r < 4; ++r)
            Hr[s][r] = Hs[pxw + s * 16 + g * 4 + r];
    float minv[2][4], min2[2][4];
    int   mini[2][4];
    #pragma unroll
    for (int s = 0; s < 2; ++s)
        #pragma unroll
        for (int r = 0; r < 4; ++r) {
            minv[s][r] = 3.4e38f; min2[s][r] = 3.4e38f; mini[s][r] = 0;
        }
    const hf* pbh = cbh + (size_t)co * 64 + g * 8;
    const hf* pbl = cbl + (size_t)co * 64 + g * 8;
    // software-pipelined main loop (2x unrolled ping-pong; code order t ascending)
    hf8 Ah0 = *(const hf8*)(pbh);
    hf8 Ah1 = *(const hf8*)(pbh + 32);
    hf8 Al0 = *(const hf8*)(pbl);
    hf8 Al1 = *(const hf8*)(pbl + 32);
    hf8 Bh0, Bh1, Bl0, Bl1;
    #pragma unroll 1
    for (int t = 0; t < 32; t += 2) {
        Bh0 = *(const hf8*)(pbh + (size_t)(t + 1) * 1024);
        Bh1 = *(const hf8*)(pbh + (size_t)(t + 1) * 1024 + 32);
        Bl0 = *(const hf8*)(pbl + (size_t)(t + 1) * 1024);
        Bl1 = *(const hf8*)(pbl + (size_t)(t + 1) * 1024 + 32);
        VQTILE(t, Ah0, Ah1, Al0, Al1);
        if (t + 2 < 32) {
            Ah0 = *(const hf8*)(pbh + (size_t)(t + 2) * 1024);
            Ah1 = *(const hf8*)(pbh + (size_t)(t + 2) * 1024 + 32);
            Al0 = *(const hf8*)(pbl + (size_t)(t + 2) * 1024);
            Al1 = *(const hf8*)(pbl + (size_t)(t + 2) * 1024 + 32);
        }
        VQTILE(t + 1, Bh0, Bh1, Bl0, Bl1);
    }
    // cross-lane top-2 merge over the 16 code-lanes (tie -> lower index)
    #pragma unroll
    for (int s = 0; s < 2; ++s)
        #pragma unroll
        for (int r = 0; r < 4; ++r) {
            float v1 = minv[s][r], v2 = min2[s][r];
            int i1 = mini[s][r];
            #pragma unroll
            for (int off = 1; off < 16; off <<= 1) {
                float vo  = __shfl_xor(v1, off, 64);
                int   io  = __shfl_xor(i1, off, 64);
                float v2o = __shfl_xor(v2, off, 64);
                if (vo < v1 || (vo == v1 && io < i1)) {
                    v2 = fminf(v1, v2o);
                    v1 = vo; i1 = io;
                } else {
                    v2 = fminf(v2, vo);
                }
            }
            if (co == 0) {
                int pxo = pxw + s * 16 + g * 4 + r;
                mis_lds[pxo] = i1;
                if (v2 - v1 <= TAU) {
                    int slot = atomicAdd(&rcnt, 1);
                    rlist[slot] = pxo;
                }
            }
        }
    __syncthreads();
    // ---- certified exact rescue (rare): full 512-code fp32 recompute, R0 chain ----
    const int nresc = rcnt;
    for (int rr = 0; rr < nresc; ++rr) {
        const int px = rlist[rr];
        const float Hp = Hs[px];
        const int c0 = tid * 2;
        float acc0 = 0.f, acc1 = 0.f;
        const float* crow0 = cb + (size_t)c0 * 64;
        const float* crow1 = crow0 + 64;
        #pragma unroll
        for (int kg = 0; kg < 16; ++kg) {
            float4 a = Ats[kg][px];
            acc0 = fmaf(a.x, crow0[kg*4+0], acc0);
            acc0 = fmaf(a.y, crow0[kg*4+1], acc0);
            acc0 = fmaf(a.z, crow0[kg*4+2], acc0);
            acc0 = fmaf(a.w, crow0[kg*4+3], acc0);
            acc1 = fmaf(a.x, crow1[kg*4+0], acc1);
            acc1 = fmaf(a.y, crow1[kg*4+1], acc1);
            acc1 = fmaf(a.z, crow1[kg*4+2], acc1);
            acc1 = fmaf(a.w, crow1[kg*4+3], acc1);
        }
        float d0 = __fadd_rn(__fsub_rn(Hp, __fmul_rn(2.f, acc0)), cn_lds[c0]);
        float d1 = __fadd_rn(__fsub_rn(Hp, __fmul_rn(2.f, acc1)), cn_lds[c0 + 1]);
        float bv = d0; int bi = c0;
        if (d1 < bv) { bv = d1; bi = c0 + 1; }
        r_v[tid] = bv; r_i[tid] = bi;
        __syncthreads();
        for (int st = 128; st > 0; st >>= 1) {
            if (tid < st) {
                float vo = r_v[tid + st]; int io = r_i[tid + st];
                if (vo < r_v[tid] || (vo == r_v[tid] && io < r_i[tid])) {
                    r_v[tid] = vo; r_i[tid] = io;
                }
            }
            __syncthreads();
        }
        if (tid == 0) mis_lds[px] = r_i[0];
        __syncthreads();
    }
    // ---- outputs + loss epilogue (exact fp32, same chain order as R0) ----
    if (tid < 128) {
        int bi = mis_lds[tid];
        idxout[base + tid] = bi;
        fidx[base + tid] = (float)bi;
        float ls = 0.f;
        const float* crow = cb + (size_t)bi * 64;
        #pragma unroll
        for (int kg = 0; kg < 16; ++kg) {
            float4 a = Ats[kg][tid];
            float d0 = crow[kg*4+0] - a.x;
            float d1 = crow[kg*4+1] - a.y;
            float d2 = crow[kg*4+2] - a.z;
            float d3 = crow[kg*4+3] - a.w;
            ls = fmaf(d0, d0, ls); ls = fmaf(d1, d1, ls);
            ls = fmaf(d2, d2, ls); ls = fmaf(d3, d3, ls);
        }
        #pragma unroll
        for (int off = 32; off > 0; off >>= 1)
            ls += __shfl_down(ls, off, 64);
        if ((tid & 63) == 0) atomicAdd(lossacc, ls);
    }
}

// ---------------- fc1: emb[512,65536] @ w1[65536,128], K-split partials ----------------
__global__ __launch_bounds__(256) void k_fc1(const int* __restrict__ idxw,
                                             const float* __restrict__ cb,
                                             const float* __restrict__ w1,
                                             float* __restrict__ part) {
    const int kchunk = blockIdx.x;       // 0..63  (16 pixels each)
    const int mtile  = blockIdx.y;       // 0..7   (64 images each)
    const int tid = threadIdx.x;
    const int wv = tid >> 6, lane = tid & 63;
    const int img = mtile * 64 + lane;
    const int pbase = kchunk * 16 + wv * 4;
    const int pbu = __builtin_amdgcn_readfirstlane(pbase);  // force uniform for s_loads
    int code[4];
    #pragma unroll
    for (int pp = 0; pp < 4; ++pp)
        code[pp] = idxw[(size_t)img * NPX + pbase + pp];
    for (int cc = 0; cc < 4; ++cc) {
        v2f acc2[16];
        #pragma unroll
        for (int c = 0; c < 16; ++c) acc2[c] = splat2(0.f);
        #pragma unroll
        for (int pp = 0; pp < 4; ++pp) {
            const float* arow = cb + (size_t)code[pp] * 64;
            const float* wrow = w1 + ((size_t)(pbu + pp) * 64) * 128 + cc * 32;
            for (int kc = 0; kc < 4; ++kc) {
                float4 a4[4];
                #pragma unroll
                for (int q = 0; q < 4; ++q)
                    a4[q] = *(const float4*)(arow + kc * 16 + q * 4);
                #pragma unroll
                for (int kk = 0; kk < 16; ++kk) {
                    float av = ((const float*)a4)[kk];
                    v2f avv = splat2(av);
                    const v2f* wr = (const v2f*)(wrow + (size_t)(kc * 16 + kk) * 128);
                    #pragma unroll
                    for (int c = 0; c < 16; ++c)
                        acc2[c] = pkfma(avv, wr[c], acc2[c]);
                }
            }
        }
        float4* pout = (float4*)(part + ((size_t)kchunk * 512 + img) * 128 + cc * 32);
        #pragma unroll
        for (int q = 0; q < 8; ++q)
            pout[q] = make_float4(acc2[q*2+0].x, acc2[q*2+0].y,
                                  acc2[q*2+1].x, acc2[q*2+1].y);
    }
}

// ---------------- reduce partials + b1 + relu -> x0 [512,128] ----------------
__global__ __launch_bounds__(256) void k_reduce(const float* __restrict__ part,
                                                const float* __restrict__ b1,
                                                float* __restrict__ x0) {
    int t = blockIdx.x * 256 + threadIdx.x;  // 0..65535
    float s = b1[t & 127];
    for (int ch = 0; ch < 64; ++ch)
        s += part[(size_t)ch * 65536 + t];
    x0[t] = fmaxf(s, 0.f);
}

// ---------------- fused trunk + heads (+ folded vq-loss finalize) ----------------
__device__ __forceinline__ void mlp_layer(const float in[][16], float out[][16],
                                          const float* __restrict__ W,
                                          const float* __restrict__ bias,
                                          int tid, bool dorelu) {
    const int lane = tid & 63, wv = tid >> 6;
    const int img = lane & 15, cg = lane >> 4;
    const int c0 = wv * 32 + cg * 8;
    float acc[8] = {0,0,0,0,0,0,0,0};
    for (int k = 0; k < 128; ++k) {
        float a = in[k][img];
        float4 wA = *(const float4*)(W + (size_t)k * 128 + c0);
        float4 wB = *(const float4*)(W + (size_t)k * 128 + c0 + 4);
        acc[0] = fmaf(a, wA.x, acc[0]);
        acc[1] = fmaf(a, wA.y, acc[1]);
        acc[2] = fmaf(a, wA.z, acc[2]);
        acc[3] = fmaf(a, wA.w, acc[3]);
        acc[4] = fmaf(a, wB.x, acc[4]);
        acc[5] = fmaf(a, wB.y, acc[5]);
        acc[6] = fmaf(a, wB.z, acc[6]);
        acc[7] = fmaf(a, wB.w, acc[7]);
    }
    #pragma unroll
    for (int c = 0; c < 8; ++c) {
        float v = acc[c] + bias[c0 + c];
        if (dorelu) v = fmaxf(v, 0.f);
        out[c0 + c][img] = v;
    }
}

__global__ __launch_bounds__(256) void k_trunk(const float* __restrict__ x0,
        const float* __restrict__ w2, const float* __restrict__ b2,
        const float* __restrict__ w3, const float* __restrict__ b3,
        const float* __restrict__ wa1, const float* __restrict__ ba1,
        const float* __restrict__ wa2, const float* __restrict__ ba2,
        const float* __restrict__ wc1, const float* __restrict__ bc1,
        const float* __restrict__ wc2, const float* __restrict__ bc2,
        const float* __restrict__ wc3, const float* __restrict__ bc3,
        float* __restrict__ probs, float* __restrict__ value,
        const float* __restrict__ accv, float* __restrict__ vqloss) {
    __shared__ float bufA[128][16], bufB[128][16], bufC[128][16];
    __shared__ float lg[16][10];
    const int tid = threadIdx.x;
    const int m0 = blockIdx.x * 16;
    if (blockIdx.x == 0 && tid == 0)     // folded k_vqfinal (k_vq complete: stream order)
        vqloss[0] = accv[0] * 1.25f / 33554432.f;
    for (int r = 0; r < 2; ++r) {
        int j = tid + r * 256;                 // 0..511
        int img = j >> 5, k4 = j & 31;
        float4 v = *(const float4*)(x0 + (size_t)(m0 + img) * 128 + k4 * 4);
        bufA[k4*4+0][img] = v.x;
        bufA[k4*4+1][img] = v.y;
        bufA[k4*4+2][img] = v.z;
        bufA[k4*4+3][img] = v.w;
    }
    __syncthreads();
    mlp_layer(bufA, bufB, w2, b2, tid, true);   __syncthreads();
    mlp_layer(bufB, bufC, w3, b3, tid, true);   __syncthreads();  // C = e3
    mlp_layer(bufC, bufA, wa1, ba1, tid, true); __syncthreads();  // A = a1
    if (tid < 160) {
        int img = tid & 15, col = tid >> 4;     // col 0..9
        float s = 0.f;
        for (int k = 0; k < 128; ++k)
            s = fmaf(bufA[k][img], wa2[(size_t)k * 10 + col], s);
        lg[img][col] = s + ba2[col];
    }
    __syncthreads();
    if (tid < 16) {
        int img = tid;
        float m = lg[img][0];
        #pragma unroll
        for (int c = 1; c < 10; ++c) m = fmaxf(m, lg[img][c]);
        float e[10]; float s = 0.f;
        #pragma unroll
        for (int c = 0; c < 10; ++c) { e[c] = expf(lg[img][c] - m); s += e[c]; }
        float inv = 1.f / s;
        #pragma unroll
        for (int c = 0; c < 10; ++c)
            probs[(size_t)(m0 + img) * 10 + c] = e[c] * inv;
    }
    __syncthreads();
    mlp_layer(bufC, bufB, wc1, bc1, tid, true); __syncthreads();
    mlp_layer(bufB, bufA, wc2, bc2, tid, true); __syncthreads();  // A = c2
    if (tid < 16) {
        int img = tid;
        float s = 0.f;
        for (int k = 0; k < 128; ++k)
            s = fmaf(bufA[k][img], wc3[k], s);
        value[m0 + img] = s + bc3[0];
    }
}

extern "C" void kernel_launch(void* const* d_in, const int* in_sizes, int n_in,
                              void* d_out, int out_size, void* d_ws, size_t ws_size,
                              hipStream_t stream) {
    const float* x   = (const float*)d_in[0];
    const float* c1w = (const float*)d_in[1];
    const float* c1b = (const float*)d_in[2];
    const float* c2w = (const float*)d_in[3];
    const float* c2b = (const float*)d_in[4];
    const float* cb  = (const float*)d_in[5];
    const float* w1  = (const float*)d_in[6];
    const float* b1  = (const float*)d_in[7];
    const float* w2  = (const float*)d_in[8];
    const float* b2  = (const float*)d_in[9];
    const float* w3  = (const float*)d_in[10];
    const float* b3  = (const float*)d_in[11];
    const float* wa1 = (const float*)d_in[12];
    const float* ba1 = (const float*)d_in[13];
    const float* wa2 = (const float*)d_in[14];
    const float* ba2 = (const float*)d_in[15];
    const float* wc1 = (const float*)d_in[16];
    const float* bc1 = (const float*)d_in[17];
    const float* wc2 = (const float*)d_in[18];
    const float* bc2 = (const float*)d_in[19];
    const float* wc3 = (const float*)d_in[20];
    const float* bc3 = (const float*)d_in[21];

    float* out = (float*)d_out;
    float* ws  = (float*)d_ws;

    // workspace layout (floats):
    float* h1    = ws;                                   // 16,777,216  (dead after conv2)
    float* part  = ws;                                   //  4,194,304  (reuses h1 region)
    float* x0    = ws + (size_t)4 * 1024 * 1024;         //     65,536  (inside dead h1)
    float* h     = ws + (size_t)16 * 1024 * 1024;        // 33,554,432
    int*   idxw  = (int*)(ws + (size_t)50331648);        //    524,288 ints
    float* cn    = ws + (size_t)50855936;                //        512
    float* accv  = ws + (size_t)50856448;                //          1
    hf*    cbh   = (hf*)(ws + (size_t)50857984);         //     32,768 f16
    hf*    cbl   = (hf*)(ws + (size_t)50874368);         //     32,768 f16

    hipLaunchKernelGGL(k_conv1,  dim3(512),   dim3(256), 0, stream, x, c1w, c1b, h1,
                       cb, cn, cbh, cbl, accv);
    hipLaunchKernelGGL(k_conv2,  dim3(2048),  dim3(512), 0, stream, h1, c2w, c2b, h);
    hipLaunchKernelGGL(k_vq,     dim3(4096),  dim3(256), 0, stream, h, cb, cbh, cbl, cn,
                       idxw, out + 5633, accv);
    hipLaunchKernelGGL(k_fc1,    dim3(64, 8), dim3(256), 0, stream, idxw, cb, w1, part);
    hipLaunchKernelGGL(k_reduce, dim3(256),   dim3(256), 0, stream, part, b1, x0);
    hipLaunchKernelGGL(k_trunk,  dim3(32),    dim3(256), 0, stream, x0,
                       w2, b2, w3, b3, wa1, ba1, wa2, ba2,
                       wc1, bc1, wc2, bc2, wc3, bc3,
                       out, out + 5120, accv, out + 5632);
}